// Round 10
// baseline (260.551 us; speedup 1.0000x reference)
//
#include <hip/hip_runtime.h>

#define TB 256
#define NA_G (32 * 12 * 1024)   // 16B-groups in A tiles
#define NB_G (64 * 12 * 1024)   // 16B-groups in B tiles
#define NEED_T ((size_t)(NA_G + NB_G) * 16)          // 18.87 MB bf16 tiles
#define NEED_S ((size_t)8192 * 4096 * 2)             // 67.1 MB bf16 S

typedef __bf16 bf16x8 __attribute__((ext_vector_type(8)));
typedef float f32x4 __attribute__((ext_vector_type(4)));
typedef unsigned u32x4 __attribute__((ext_vector_type(4)));
typedef unsigned u32x2 __attribute__((ext_vector_type(2)));
typedef unsigned long long ull;

__device__ __forceinline__ unsigned pack2bf(float a, float b) {
  unsigned ua = __float_as_uint(a), ub = __float_as_uint(b);
  ua = (ua + 0x7fffu + ((ua >> 16) & 1u)) >> 16;   // RNE f32->bf16
  ub = (ub + 0x7fffu + ((ub >> 16) & 1u)) >> 16;
  return ua | (ub << 16);
}
__device__ __forceinline__ unsigned akey16(unsigned bits) {
  return (bits & 0x8000u) ? (bits ^ 0xFFFFu) : (bits | 0x8000u);
}
__device__ __forceinline__ float akey2f(unsigned ak) {
  unsigned bits = (ak & 0x8000u) ? (ak ^ 0x8000u) : (ak ^ 0xFFFFu);
  return __uint_as_float(bits << 16);
}
__device__ __forceinline__ float bf2f(unsigned bits) {
  return __uint_as_float(bits << 16);
}
__device__ __forceinline__ void gll16(const void* g, void* l) {
  __builtin_amdgcn_global_load_lds(
      (const __attribute__((address_space(1))) unsigned*)g,
      (__attribute__((address_space(3))) unsigned*)l, 16, 0, 0);
}

// Pre-convert f32 -> bf16 into XOR-swizzled 128x64 tiles (LDS-image layout)
__global__ __launch_bounds__(256) void convert_pack(
    const float* __restrict__ q, const float* __restrict__ p,
    unsigned char* __restrict__ qt, unsigned char* __restrict__ pt) {
  int g = blockIdx.x * 256 + threadIdx.x;
  const float* src;
  unsigned char* dst;
  if (g < NA_G) { src = q; dst = qt; }
  else { g -= NA_G; src = p; dst = pt; }
  int tile = g >> 10;
  int o = (g & 1023) * 16;
  int row = o >> 7;
  int colb = (o & 127) ^ ((row & 7) << 4);
  int rb = tile / 12, kt = tile - rb * 12;
  const float* s = src + ((size_t)(rb * 128 + row)) * 768 + kt * 64 + (colb >> 1);
  float4 a = ((const float4*)s)[0];
  float4 b = ((const float4*)s)[1];
  uint4 w;
  w.x = pack2bf(a.x, a.y); w.y = pack2bf(a.z, a.w);
  w.z = pack2bf(b.x, b.y); w.w = pack2bf(b.z, b.w);
  *(uint4*)(dst + (size_t)tile * 16384 + o) = w;
}

// ========== kernel 1: LDS-staged GEMM -> S (bf16, coalesced NT stores) ==========
template <int PATH>
__global__ __launch_bounds__(TB, 4) void dpr_gemm(
    const float* __restrict__ q_emb, const float* __restrict__ p_emb,
    const unsigned char* __restrict__ qt, const unsigned char* __restrict__ pt,
    unsigned short* __restrict__ Sout) {
  __shared__ __align__(16) char arena[32768];
  unsigned short* Al = (unsigned short*)arena;
  unsigned short* Bl = (unsigned short*)(arena + 16384);

  const int tid = threadIdx.x, lane = tid & 63, wid = tid >> 6;
  int g = blockIdx.x;
  int rg = g & 7, w = g >> 3;
  int blockB = (rg >> 2) * 16 + (w & 15);
  int blockP = (rg & 3) * 16 + (w >> 4);
  const int lr = lane & 15, lg = lane >> 4;
  const int db = wid >> 1, dp = wid & 1;

  f32x4 acc[4][4];
  #pragma unroll
  for (int m = 0; m < 4; ++m)
    #pragma unroll
    for (int n = 0; n < 4; ++n)
      acc[m][n] = f32x4{0.f, 0.f, 0.f, 0.f};

  const float* Abase = q_emb + (size_t)(blockB * 128) * 768;
  const float* Bbase = p_emb + (size_t)(blockP * 128) * 768;

  for (int kt = 0; kt < 12; ++kt) {
    if (PATH == 1) {
      const unsigned char* qtile = qt + ((size_t)(blockB * 12 + kt)) * 16384;
      const unsigned char* ptile = pt + ((size_t)(blockP * 12 + kt)) * 16384;
      #pragma unroll
      for (int c2 = 0; c2 < 4; ++c2) {
        int chunk = wid * 4 + c2;
        gll16(qtile + chunk * 1024 + lane * 16, (char*)Al + chunk * 1024);
        gll16(ptile + chunk * 1024 + lane * 16, (char*)Bl + chunk * 1024);
      }
    } else {
      const int k0 = kt * 64;
      #pragma unroll
      for (int it = 0; it < 4; ++it) {
        int gg = tid + 256 * it;
        int row = gg >> 3;
        int col = (gg & 7) * 8;
        int off = (row * 128 + col * 2) ^ ((row & 7) << 4);
        const float4* sA = (const float4*)(Abase + (size_t)row * 768 + k0 + col);
        float4 a0 = sA[0], a1 = sA[1];
        uint4 wv;
        wv.x = pack2bf(a0.x, a0.y); wv.y = pack2bf(a0.z, a0.w);
        wv.z = pack2bf(a1.x, a1.y); wv.w = pack2bf(a1.z, a1.w);
        *(uint4*)((char*)Al + off) = wv;
        const float4* sB = (const float4*)(Bbase + (size_t)row * 768 + k0 + col);
        float4 b0 = sB[0], b1 = sB[1];
        wv.x = pack2bf(b0.x, b0.y); wv.y = pack2bf(b0.z, b0.w);
        wv.z = pack2bf(b1.x, b1.y); wv.w = pack2bf(b1.z, b1.w);
        *(uint4*)((char*)Bl + off) = wv;
      }
    }
    __syncthreads();
    #pragma unroll
    for (int ks = 0; ks < 2; ++ks) {
      bf16x8 af[4], bfr[4];
      #pragma unroll
      for (int m = 0; m < 4; ++m) {
        int row = db * 64 + m * 16 + lr;
        int off = (row * 128 + ks * 64 + lg * 16) ^ ((row & 7) << 4);
        af[m] = *(const bf16x8*)((const char*)Al + off);
      }
      #pragma unroll
      for (int n = 0; n < 4; ++n) {
        int row = dp * 64 + n * 16 + lr;
        int off = (row * 128 + ks * 64 + lg * 16) ^ ((row & 7) << 4);
        bfr[n] = *(const bf16x8*)((const char*)Bl + off);
      }
      #pragma unroll
      for (int m = 0; m < 4; ++m)
        #pragma unroll
        for (int n = 0; n < 4; ++n)
          acc[m][n] = __builtin_amdgcn_mfma_f32_16x16x32_bf16(af[m], bfr[n], acc[m][n], 0, 0, 0);
    }
    __syncthreads();
  }

  // epilogue: stage S quadrant in LDS (XOR-swizzled), stream out coalesced NT
  char* Sq = arena + wid * 8192;
  #pragma unroll
  for (int m = 0; m < 4; ++m)
    #pragma unroll
    for (int n = 0; n < 4; ++n) {
      int row = n * 16 + lr;
      int byte = row * 128 + m * 32 + lg * 8;
      int swz = byte ^ ((row & 7) << 4);
      u32x2 wv;
      wv.x = pack2bf(acc[m][n][0], acc[m][n][1]);
      wv.y = pack2bf(acc[m][n][2], acc[m][n][3]);
      *(u32x2*)(Sq + swz) = wv;
    }
  const int pair = (blockB * 2 + db) * 128 + blockP * 2 + dp;
  unsigned short* Sp = Sout + ((size_t)pair << 12);
  #pragma unroll
  for (int i = 0; i < 8; ++i) {
    int base = i * 1024 + lane * 16;
    int swz = base ^ ((lane >> 3) << 4);
    u32x4 v = *(const u32x4*)(Sq + swz);
    __builtin_nontemporal_store(v, (u32x4*)((char*)Sp + base));
  }
}

// ==== kernel 2: key-space 2-level count+sum histogram selection (exact) ====
#define FOREACH_VALID(BODY)                                   \
  _Pragma("unroll") for (int t = 0; t < 8; ++t) {             \
    if ((pm8 >> t) & 1u) {                                    \
      _Pragma("unroll") for (int jj = 0; jj < 8; ++jj) {      \
        if ((qm8 >> jj) & 1u) {                               \
          unsigned u = vv[t][jj >> 1];                        \
          unsigned bits = (jj & 1) ? (u >> 16) : (u & 0xFFFFu); \
          BODY                                                \
        } } } }

__global__ __launch_bounds__(TB, 4) void dpr_select(
    const unsigned short* __restrict__ S,
    const void* __restrict__ qmr, const void* __restrict__ pmr,
    const float* __restrict__ alpha_raw, const float* __restrict__ beta_raw,
    float* __restrict__ out) {
  __shared__ unsigned l1c[4][1024];
  __shared__ float    l1s[4][1024];
  __shared__ unsigned l2c[4][128];    // [0:64) top bin subs, [64:128) bottom
  __shared__ float    l2s[4][128];

  const int tid = threadIdx.x, lane = tid & 63, wid = tid >> 6;
  const int pair = blockIdx.x * 4 + wid;
  const int b = pair >> 7, p = pair & 127;

  bool m32 = true;
  {
    const unsigned* qm32 = (const unsigned*)qmr;
    #pragma unroll
    for (int i = 0; i < 8; ++i) m32 = m32 && (qm32[i] <= 1u);
  }
  bool qvb = m32 ? (((const int*)qmr)[b * 64 + lane] != 0)
                 : (((const unsigned char*)qmr)[b * 64 + lane] != 0);
  bool pvb = m32 ? (((const int*)pmr)[p * 64 + lane] != 0)
                 : (((const unsigned char*)pmr)[p * 64 + lane] != 0);
  ull qb = __ballot(qvb);
  ull pb = __ballot(pvb);
  const int n_pair = __popcll(qb) * __popcll(pb);
  if (n_pair == 0) {
    if (lane == 0) out[pair] = -1e9f;
    return;
  }

  int ksel = 4 * n_pair / 10; if (ksel < 1) ksel = 1;
  int lsel = 2 * n_pair / 10; if (lsel < 1) lsel = 1;

  // load this pair's 64 values / lane ONCE into registers
  const unsigned short* Sp = S + ((size_t)pair << 12);
  u32x4 vv[8];
  #pragma unroll
  for (int t = 0; t < 8; ++t)
    vv[t] = __builtin_nontemporal_load((const u32x4*)(Sp + t * 512 + lane * 8));

  const unsigned qm8 = (unsigned)((qb >> ((lane & 7) * 8)) & 0xFFull);
  unsigned pm8 = 0;
  #pragma unroll
  for (int t = 0; t < 8; ++t)
    pm8 |= (unsigned)((pb >> (t * 8 + (lane >> 3))) & 1ull) << t;

  unsigned* c1 = l1c[wid]; float* s1 = l1s[wid];
  unsigned* c2 = l2c[wid]; float* s2 = l2s[wid];

  // zero (wave-private; same-wave LDS ops are in-order)
  #pragma unroll
  for (int i = 0; i < 4; ++i) {
    ((uint4*)c1)[lane + 64 * i] = uint4{0u, 0u, 0u, 0u};
    ((f32x4*)s1)[lane + 64 * i] = f32x4{0.f, 0.f, 0.f, 0.f};
  }
  ((u32x2*)c2)[lane] = u32x2{0u, 0u};
  ((u32x2*)s2)[lane] = u32x2{0u, 0u};

  // T1: the ONLY full traversal — 10-bit key bin count+sum histogram
  FOREACH_VALID({
    unsigned ak = akey16(bits);
    unsigned bin = ak >> 6;
    atomicAdd(&c1[bin], 1u);
    atomicAdd(&s1[bin], bf2f(bits));
  })

  // L1 scan: lane owns bins [lane*16, lane*16+16)
  unsigned cl[16]; float sl[16];
  #pragma unroll
  for (int i2 = 0; i2 < 4; ++i2) {
    uint4 cq = ((const uint4*)c1)[lane * 4 + i2];
    f32x4 sq = ((const f32x4*)s1)[lane * 4 + i2];
    cl[i2 * 4 + 0] = cq.x; cl[i2 * 4 + 1] = cq.y;
    cl[i2 * 4 + 2] = cq.z; cl[i2 * 4 + 3] = cq.w;
    sl[i2 * 4 + 0] = sq[0]; sl[i2 * 4 + 1] = sq[1];
    sl[i2 * 4 + 2] = sq[2]; sl[i2 * 4 + 3] = sq[3];
  }
  unsigned lc = 0; float ls = 0.f;
  #pragma unroll
  for (int i = 0; i < 16; ++i) { lc += cl[i]; ls += sl[i]; }
  unsigned runC = lc; float runS = ls;
  #pragma unroll
  for (int off = 1; off < 64; off <<= 1) {
    unsigned o = __shfl_down(runC, off);
    float os = __shfl_down(runS, off);
    if (lane + off < 64) { runC += o; runS += os; }
  }
  const unsigned totC = __shfl(runC, 0);
  const float tsum = __shfl(runS, 0);   // masked total sum, free from the scan

  // top: suffix location
  unsigned aboveC = runC - lc; float aboveS = runS - ls;
  bool fT = ((unsigned)ksel > aboveC) && ((unsigned)ksel <= runC);
  int sbT_ = 0, RT_ = 0; float saT_ = 0.f;
  {
    unsigned a = aboveC; float va = aboveS; bool done = false;
    #pragma unroll
    for (int i = 15; i >= 0; --i) {
      if (fT && !done && (unsigned)ksel <= a + cl[i]) {
        sbT_ = lane * 16 + i; RT_ = (int)((unsigned)ksel - a); saT_ = va; done = true;
      }
      if (!done) { a += cl[i]; va += sl[i]; }
    }
  }
  ull fmT = __ballot(fT);
  int srcT = fmT ? (int)__builtin_ctzll(fmT) : 0;
  const int sbT = __shfl(sbT_, srcT);
  const int RT = __shfl(RT_, srcT);
  const float saT = __shfl(saT_, srcT);

  // bottom: prefix location
  unsigned belowC = totC - runC; float belowS = tsum - runS;
  bool fB = ((unsigned)lsel > belowC) && ((unsigned)lsel <= belowC + lc);
  int sbB_ = 0, RB_ = 0; float saB_ = 0.f;
  {
    unsigned a = belowC; float vb = belowS; bool done = false;
    #pragma unroll
    for (int i = 0; i < 16; ++i) {
      if (fB && !done && (unsigned)lsel <= a + cl[i]) {
        sbB_ = lane * 16 + i; RB_ = (int)((unsigned)lsel - a); saB_ = vb; done = true;
      }
      if (!done) { a += cl[i]; vb += sl[i]; }
    }
  }
  ull fmB = __ballot(fB);
  int srcB = fmB ? (int)__builtin_ctzll(fmB) : 0;
  const int sbB = __shfl(sbB_, srcB);
  const int RB = __shfl(RB_, srcB);
  const float saB = __shfl(saB_, srcB);

  // L2: one light predicated traversal filling both 64-bin sub-hists
  FOREACH_VALID({
    unsigned ak = akey16(bits);
    unsigned hb = ak >> 6;
    unsigned sub = ak & 63u;
    if (hb == (unsigned)sbT) { atomicAdd(&c2[sub], 1u); atomicAdd(&s2[sub], bf2f(bits)); }
    if (hb == (unsigned)sbB) { atomicAdd(&c2[64 + sub], 1u); atomicAdd(&s2[64 + sub], bf2f(bits)); }
  })

  // L2 top: suffix over 64 sub-bins (1/lane); all elems in a sub-bin are EQUAL
  float inT;
  {
    unsigned cA = c2[lane]; float sA = s2[lane];
    unsigned rA = cA; float rAs = sA;
    #pragma unroll
    for (int off = 1; off < 64; off <<= 1) {
      unsigned o = __shfl_down(rA, off);
      float os = __shfl_down(rAs, off);
      if (lane + off < 64) { rA += o; rAs += os; }
    }
    unsigned aA = rA - cA; float aAs = rAs - sA;
    bool f = ((unsigned)RT > aA) && ((unsigned)RT <= rA);
    float v = 0.f;
    if (f) {
      int R3 = RT - (int)aA;
      unsigned akT = ((unsigned)sbT << 6) | (unsigned)lane;
      v = aAs + akey2f(akT) * (float)R3;    // exact: tie group is bit-identical
    }
    ull fm = __ballot(f);
    int sc = fm ? (int)__builtin_ctzll(fm) : 0;
    inT = __shfl(v, sc);
  }
  // L2 bottom: prefix
  float inB;
  {
    unsigned cB2 = c2[64 + lane]; float sB2 = s2[64 + lane];
    unsigned rB = cB2; float rBs = sB2;
    #pragma unroll
    for (int off = 1; off < 64; off <<= 1) {
      unsigned o = __shfl_up(rB, off);
      float os = __shfl_up(rBs, off);
      if (lane >= off) { rB += o; rBs += os; }
    }
    unsigned bB = rB - cB2; float bBs = rBs - sB2;
    bool f = ((unsigned)RB > bB) && ((unsigned)RB <= rB);
    float v = 0.f;
    if (f) {
      int R3 = RB - (int)bB;
      unsigned akB = ((unsigned)sbB << 6) | (unsigned)lane;
      v = bBs + akey2f(akB) * (float)R3;
    }
    ull fm = __ballot(f);
    int sc = fm ? (int)__builtin_ctzll(fm) : 0;
    inB = __shfl(v, sc);
  }

  if (lane == 0) {
    float top_sum = saT + inT;
    float bot_sum = saB + inB;
    float alpha = log1pf(expf(alpha_raw[0]));
    float beta = log1pf(expf(beta_raw[0]));
    float total_mean = tsum / (float)n_pair;
    float top_mean = top_sum / (float)ksel;
    float bm = fmaxf(0.0f, -(bot_sum / (float)lsel));
    out[pair] = total_mean + alpha * top_mean - beta * bm;
  }
}
#undef FOREACH_VALID

// ========== last-resort fused fallback (no workspace) ==========
__device__ __forceinline__ void scanTopSum(const unsigned* hC, const float* hS,
                                           int lane, int R, int& selB, int& Rin,
                                           int& cnt, float& sumAbove, float& binSum) {
  uint4 c4 = ((const uint4*)hC)[lane];
  float4 s4 = ((const float4*)hS)[lane];
  unsigned lc = c4.x + c4.y + c4.z + c4.w;
  float ls = s4.x + s4.y + s4.z + s4.w;
  unsigned run = lc; float runv = ls;
  #pragma unroll
  for (int off = 1; off < 64; off <<= 1) {
    unsigned o = __shfl_down(run, off);
    float ov = __shfl_down(runv, off);
    if (lane + off < 64) { run += o; runv += ov; }
  }
  unsigned above = run - lc; float vabove = runv - ls;
  bool found = ((unsigned)R > above) && ((unsigned)R <= run);
  int sb = 0, ri = 0, cc = 0; float sa = 0.f, bs = 0.f;
  if (found) {
    unsigned a = above; float va = vabove;
    if ((unsigned)R <= a + c4.w) { sb = 3; ri = R - (int)a; cc = (int)c4.w; sa = va; bs = s4.w; }
    else { a += c4.w; va += s4.w;
    if ((unsigned)R <= a + c4.z) { sb = 2; ri = R - (int)a; cc = (int)c4.z; sa = va; bs = s4.z; }
    else { a += c4.z; va += s4.z;
    if ((unsigned)R <= a + c4.y) { sb = 1; ri = R - (int)a; cc = (int)c4.y; sa = va; bs = s4.y; }
    else { a += c4.y; va += s4.y; sb = 0; ri = R - (int)a; cc = (int)c4.x; sa = va; bs = s4.x; } } }
    sb += lane * 4;
  }
  ull fm = __ballot(found);
  int src = fm ? (int)__builtin_ctzll(fm) : 0;
  selB = __shfl(sb, src); Rin = __shfl(ri, src);
  cnt = __shfl(cc, src); sumAbove = __shfl(sa, src); binSum = __shfl(bs, src);
}

__device__ __forceinline__ void scanBotSum(const unsigned* hC, const float* hS,
                                           int lane, int R, int& selB, int& Rin,
                                           int& cnt, float& sumBelow, float& binSum) {
  uint4 c4 = ((const uint4*)hC)[lane];
  float4 s4 = ((const float4*)hS)[lane];
  unsigned lc = c4.x + c4.y + c4.z + c4.w;
  float ls = s4.x + s4.y + s4.z + s4.w;
  unsigned run = lc; float runv = ls;
  #pragma unroll
  for (int off = 1; off < 64; off <<= 1) {
    unsigned o = __shfl_up(run, off);
    float ov = __shfl_up(runv, off);
    if (lane >= off) { run += o; runv += ov; }
  }
  unsigned below = run - lc; float vbelow = runv - ls;
  bool found = ((unsigned)R > below) && ((unsigned)R <= run);
  int sb = 0, ri = 0, cc = 0; float sa = 0.f, bs = 0.f;
  if (found) {
    unsigned a = below; float va = vbelow;
    if ((unsigned)R <= a + c4.x) { sb = 0; ri = R - (int)a; cc = (int)c4.x; sa = va; bs = s4.x; }
    else { a += c4.x; va += s4.x;
    if ((unsigned)R <= a + c4.y) { sb = 1; ri = R - (int)a; cc = (int)c4.y; sa = va; bs = s4.y; }
    else { a += c4.y; va += s4.y;
    if ((unsigned)R <= a + c4.z) { sb = 2; ri = R - (int)a; cc = (int)c4.z; sa = va; bs = s4.z; }
    else { a += c4.z; va += s4.z; sb = 3; ri = R - (int)a; cc = (int)c4.w; sa = va; bs = s4.w; } } }
    sb += lane * 4;
  }
  ull fm = __ballot(found);
  int src = fm ? (int)__builtin_ctzll(fm) : 0;
  selB = __shfl(sb, src); Rin = __shfl(ri, src);
  cnt = __shfl(cc, src); sumBelow = __shfl(sa, src); binSum = __shfl(bs, src);
}

__global__ __launch_bounds__(TB, 3) void dpr_fused0(
    const float* __restrict__ q_emb, const float* __restrict__ p_emb,
    const void* __restrict__ qmr, const void* __restrict__ pmr,
    const float* __restrict__ alpha_raw, const float* __restrict__ beta_raw,
    float* __restrict__ out) {
  __shared__ __align__(16) char arena[32768];
  unsigned short* Al = (unsigned short*)arena;
  unsigned short* Bl = (unsigned short*)(arena + 16384);
  const int tid = threadIdx.x, lane = tid & 63, wid = tid >> 6;
  const int bid = blockIdx.x, blockB = bid >> 6, blockP = bid & 63;
  const int lr = lane & 15, lg = lane >> 4;
  const int db = wid >> 1, dp = wid & 1;

  bool m32 = true;
  {
    const unsigned* qm32 = (const unsigned*)qmr;
    #pragma unroll
    for (int i = 0; i < 8; ++i) m32 = m32 && (qm32[i] <= 1u);
  }
  int qrow = (blockB * 2 + db) * 64 + lane;
  int pcolg = (blockP * 2 + dp) * 64 + lane;
  bool qvb = m32 ? (((const int*)qmr)[qrow] != 0) : (((const unsigned char*)qmr)[qrow] != 0);
  bool pvb = m32 ? (((const int*)pmr)[pcolg] != 0) : (((const unsigned char*)pmr)[pcolg] != 0);
  ull qb = __ballot(qvb);
  ull pb = __ballot(pvb);
  const int n_pair = __popcll(qb) * __popcll(pb);

  f32x4 acc[4][4];
  #pragma unroll
  for (int m = 0; m < 4; ++m)
    #pragma unroll
    for (int n = 0; n < 4; ++n)
      acc[m][n] = f32x4{0.f, 0.f, 0.f, 0.f};

  const float* Abase = q_emb + (size_t)(blockB * 128) * 768;
  const float* Bbase = p_emb + (size_t)(blockP * 128) * 768;

  for (int kt = 0; kt < 12; ++kt) {
    const int k0 = kt * 64;
    #pragma unroll
    for (int it = 0; it < 4; ++it) {
      int gg = tid + 256 * it;
      int row = gg >> 3;
      int col = (gg & 7) * 8;
      int off = (row * 128 + col * 2) ^ ((row & 7) << 4);
      const float4* sA = (const float4*)(Abase + (size_t)row * 768 + k0 + col);
      float4 a0 = sA[0], a1 = sA[1];
      uint4 wv;
      wv.x = pack2bf(a0.x, a0.y); wv.y = pack2bf(a0.z, a0.w);
      wv.z = pack2bf(a1.x, a1.y); wv.w = pack2bf(a1.z, a1.w);
      *(uint4*)((char*)Al + off) = wv;
      const float4* sB = (const float4*)(Bbase + (size_t)row * 768 + k0 + col);
      float4 b0 = sB[0], b1 = sB[1];
      wv.x = pack2bf(b0.x, b0.y); wv.y = pack2bf(b0.z, b0.w);
      wv.z = pack2bf(b1.x, b1.y); wv.w = pack2bf(b1.z, b1.w);
      *(uint4*)((char*)Bl + off) = wv;
    }
    __syncthreads();
    #pragma unroll
    for (int ks = 0; ks < 2; ++ks) {
      bf16x8 af[4], bfr[4];
      #pragma unroll
      for (int m = 0; m < 4; ++m) {
        int row = db * 64 + m * 16 + lr;
        int off = (row * 128 + ks * 64 + lg * 16) ^ ((row & 7) << 4);
        af[m] = *(const bf16x8*)((const char*)Al + off);
      }
      #pragma unroll
      for (int n = 0; n < 4; ++n) {
        int row = dp * 64 + n * 16 + lr;
        int off = (row * 128 + ks * 64 + lg * 16) ^ ((row & 7) << 4);
        bfr[n] = *(const bf16x8*)((const char*)Bl + off);
      }
      #pragma unroll
      for (int m = 0; m < 4; ++m)
        #pragma unroll
        for (int n = 0; n < 4; ++n)
          acc[m][n] = __builtin_amdgcn_mfma_f32_16x16x32_bf16(af[m], bfr[n], acc[m][n], 0, 0, 0);
    }
    __syncthreads();
  }

  const int outIdx = (blockB * 2 + db) * 128 + (blockP * 2 + dp);
  if (n_pair == 0) {
    if (lane == 0) out[outIdx] = -1e9f;
    return;
  }

  unsigned vlo = 0, vhi = 0;
  {
    unsigned qn[4], pc[4];
    #pragma unroll
    for (int m = 0; m < 4; ++m) qn[m] = (unsigned)((qb >> (m * 16 + lg * 4)) & 0xFull);
    #pragma unroll
    for (int n = 0; n < 4; ++n) pc[n] = ((pb >> (n * 16 + lr)) & 1ull) ? 0xFu : 0u;
    #pragma unroll
    for (int m = 0; m < 2; ++m)
      #pragma unroll
      for (int n = 0; n < 4; ++n) vlo |= (qn[m] & pc[n]) << ((m * 4 + n) * 4);
    #pragma unroll
    for (int m = 2; m < 4; ++m)
      #pragma unroll
      for (int n = 0; n < 4; ++n) vhi |= (qn[m] & pc[n]) << (((m - 2) * 4 + n) * 4);
  }
  #define VBIT(idx) ((idx) < 32 ? ((vlo >> (idx)) & 1u) : ((vhi >> ((idx) - 32)) & 1u))

  float tsum = 0.f, mn = INFINITY, mx = -INFINITY;
  #pragma unroll
  for (int m = 0; m < 4; ++m)
    #pragma unroll
    for (int n = 0; n < 4; ++n)
      #pragma unroll
      for (int j = 0; j < 4; ++j) {
        const int idx = (m * 4 + n) * 4 + j;
        float x = acc[m][n][j];
        if (VBIT(idx)) { tsum += x; mn = fminf(mn, x); mx = fmaxf(mx, x); }
      }
  #pragma unroll
  for (int off = 1; off < 64; off <<= 1) {
    tsum += __shfl_xor(tsum, off);
    mn = fminf(mn, __shfl_xor(mn, off));
    mx = fmaxf(mx, __shfl_xor(mx, off));
  }

  int ksel = 4 * n_pair / 10; if (ksel < 1) ksel = 1;
  int lsel = 2 * n_pair / 10; if (lsel < 1) lsel = 1;

  unsigned* hC = (unsigned*)(arena + wid * 2048);
  float* hS = (float*)(arena + wid * 2048 + 1024);

  float topS, botS;
  if (!(mx > mn)) {
    topS = (float)ksel * mn;
    botS = (float)lsel * mn;
  } else {
    const float w0 = (mx - mn) * (1.0f / 256.0f);
    const float sc0 = 1.0f / w0;
    ((uint4*)hC)[lane] = uint4{0u, 0u, 0u, 0u};
    ((float4*)hS)[lane] = float4{0.f, 0.f, 0.f, 0.f};
    #pragma unroll
    for (int m = 0; m < 4; ++m)
      #pragma unroll
      for (int n = 0; n < 4; ++n)
        #pragma unroll
        for (int j = 0; j < 4; ++j) {
          const int idx = (m * 4 + n) * 4 + j;
          if (VBIT(idx)) {
            float x = acc[m][n][j];
            int bn = (int)((x - mn) * sc0);
            bn = bn < 0 ? 0 : (bn > 255 ? 255 : bn);
            atomicAdd(&hC[bn], 1u);
            atomicAdd(&hS[bn], x);
          }
        }
    int sbT, RT, cT; float sumA, sBinT;
    int sbB, RB, cB; float sumBlw, sBinB;
    scanTopSum(hC, hS, lane, ksel, sbT, RT, cT, sumA, sBinT);
    scanBotSum(hC, hS, lane, lsel, sbB, RB, cB, sumBlw, sBinB);

    auto refine = [&](bool largest, int sb0, int R0, int c0, float binSum0) -> float {
      if (R0 >= c0) return binSum0;
      float lo1 = mn + w0 * (float)sb0;
      if (!(w0 > 0.f)) return binSum0 * ((float)R0 / (float)c0);
      ((uint4*)hC)[lane] = uint4{0u, 0u, 0u, 0u};
      ((float4*)hS)[lane] = float4{0.f, 0.f, 0.f, 0.f};
      const float sc1 = 256.0f / w0;
      #pragma unroll
      for (int m = 0; m < 4; ++m)
        #pragma unroll
        for (int n = 0; n < 4; ++n)
          #pragma unroll
          for (int j = 0; j < 4; ++j) {
            const int idx = (m * 4 + n) * 4 + j;
            if (VBIT(idx)) {
              float x = acc[m][n][j];
              int b0e = (int)((x - mn) * sc0);
              b0e = b0e < 0 ? 0 : (b0e > 255 ? 255 : b0e);
              if (b0e == sb0) {
                int b1 = (int)((x - lo1) * sc1);
                b1 = b1 < 0 ? 0 : (b1 > 255 ? 255 : b1);
                atomicAdd(&hC[b1], 1u);
                atomicAdd(&hS[b1], x);
              }
            }
          }
      int sb2, R2, c2; float above2, bs2;
      if (largest) scanTopSum(hC, hS, lane, R0, sb2, R2, c2, above2, bs2);
      else         scanBotSum(hC, hS, lane, R0, sb2, R2, c2, above2, bs2);
      if (c2 <= 0) return binSum0 * ((float)R0 / (float)c0);
      return above2 + bs2 * ((float)R2 / (float)c2);
    };

    topS = sumA + refine(true, sbT, RT, cT, sBinT);
    botS = sumBlw + refine(false, sbB, RB, cB, sBinB);
  }
  #undef VBIT

  if (lane == 0) {
    float alpha = log1pf(expf(alpha_raw[0]));
    float beta = log1pf(expf(beta_raw[0]));
    float total_mean = tsum / (float)n_pair;
    float top_mean = topS / (float)ksel;
    float bm = fmaxf(0.0f, -(botS / (float)lsel));
    out[outIdx] = total_mean + alpha * top_mean - beta * bm;
  }
}

extern "C" void kernel_launch(void* const* d_in, const int* in_sizes, int n_in,
                              void* d_out, int out_size, void* d_ws, size_t ws_size,
                              hipStream_t stream) {
  (void)in_sizes; (void)n_in; (void)out_size;
  const float* q_emb = (const float*)d_in[0];
  const float* p_emb = (const float*)d_in[1];
  const void* q_mask = d_in[2];
  const void* p_mask = d_in[3];
  const float* alpha_raw = (const float*)d_in[4];
  const float* beta_raw = (const float*)d_in[5];
  float* out = (float*)d_out;

  if (ws_size >= NEED_T + NEED_S) {
    unsigned char* qt = (unsigned char*)d_ws;
    unsigned char* pt = qt + (size_t)NA_G * 16;
    unsigned short* Sb = (unsigned short*)((unsigned char*)d_ws + NEED_T);
    hipLaunchKernelGGL(convert_pack, dim3((NA_G + NB_G) / 256), dim3(256), 0, stream,
                       q_emb, p_emb, qt, pt);
    hipLaunchKernelGGL((dpr_gemm<1>), dim3(2048), dim3(TB), 0, stream,
                       q_emb, p_emb, qt, pt, Sb);
    hipLaunchKernelGGL(dpr_select, dim3(2048), dim3(TB), 0, stream,
                       Sb, q_mask, p_mask, alpha_raw, beta_raw, out);
  } else if (ws_size >= NEED_S) {
    unsigned short* Sb = (unsigned short*)d_ws;
    hipLaunchKernelGGL((dpr_gemm<0>), dim3(2048), dim3(TB), 0, stream,
                       q_emb, p_emb,
                       (const unsigned char*)nullptr, (const unsigned char*)nullptr, Sb);
    hipLaunchKernelGGL(dpr_select, dim3(2048), dim3(TB), 0, stream,
                       Sb, q_mask, p_mask, alpha_raw, beta_raw, out);
  } else {
    hipLaunchKernelGGL(dpr_fused0, dim3(2048), dim3(TB), 0, stream,
                       q_emb, p_emb, q_mask, p_mask, alpha_raw, beta_raw, out);
  }
}

// Round 11
// 236.445 us; speedup vs baseline: 1.1020x; 1.1020x over previous
//
#include <hip/hip_runtime.h>

#define TB 256
#define NA_G (32 * 12 * 1024)   // 16B-groups in A tiles
#define NB_G (64 * 12 * 1024)   // 16B-groups in B tiles
#define NEED_T ((size_t)(NA_G + NB_G) * 16)          // 18.87 MB bf16 tiles
#define NEED_S ((size_t)8192 * 4096 * 2)             // 67.1 MB bf16 S

typedef __bf16 bf16x8 __attribute__((ext_vector_type(8)));
typedef float f32x4 __attribute__((ext_vector_type(4)));
typedef unsigned u32x4 __attribute__((ext_vector_type(4)));
typedef unsigned u32x2 __attribute__((ext_vector_type(2)));
typedef unsigned long long ull;

__device__ __forceinline__ unsigned pack2bf(float a, float b) {
  unsigned ua = __float_as_uint(a), ub = __float_as_uint(b);
  ua = (ua + 0x7fffu + ((ua >> 16) & 1u)) >> 16;   // RNE f32->bf16
  ub = (ub + 0x7fffu + ((ub >> 16) & 1u)) >> 16;
  return ua | (ub << 16);
}
__device__ __forceinline__ float bf2f(unsigned bits) {
  return __uint_as_float(bits << 16);
}
__device__ __forceinline__ void gll16(const void* g, void* l) {
  __builtin_amdgcn_global_load_lds(
      (const __attribute__((address_space(1))) unsigned*)g,
      (__attribute__((address_space(3))) unsigned*)l, 16, 0, 0);
}

// Pre-convert f32 -> bf16 into XOR-swizzled 128x64 tiles (LDS-image layout)
__global__ __launch_bounds__(256) void convert_pack(
    const float* __restrict__ q, const float* __restrict__ p,
    unsigned char* __restrict__ qt, unsigned char* __restrict__ pt) {
  int g = blockIdx.x * 256 + threadIdx.x;
  const float* src;
  unsigned char* dst;
  if (g < NA_G) { src = q; dst = qt; }
  else { g -= NA_G; src = p; dst = pt; }
  int tile = g >> 10;
  int o = (g & 1023) * 16;
  int row = o >> 7;
  int colb = (o & 127) ^ ((row & 7) << 4);
  int rb = tile / 12, kt = tile - rb * 12;
  const float* s = src + ((size_t)(rb * 128 + row)) * 768 + kt * 64 + (colb >> 1);
  float4 a = ((const float4*)s)[0];
  float4 b = ((const float4*)s)[1];
  uint4 w;
  w.x = pack2bf(a.x, a.y); w.y = pack2bf(a.z, a.w);
  w.z = pack2bf(b.x, b.y); w.w = pack2bf(b.z, b.w);
  *(uint4*)(dst + (size_t)tile * 16384 + o) = w;
}

// ========== kernel 1: LDS-staged GEMM -> S (bf16, coalesced NT stores) ==========
template <int PATH>
__global__ __launch_bounds__(TB, 4) void dpr_gemm(
    const float* __restrict__ q_emb, const float* __restrict__ p_emb,
    const unsigned char* __restrict__ qt, const unsigned char* __restrict__ pt,
    unsigned short* __restrict__ Sout) {
  __shared__ __align__(16) char arena[32768];
  unsigned short* Al = (unsigned short*)arena;
  unsigned short* Bl = (unsigned short*)(arena + 16384);

  const int tid = threadIdx.x, lane = tid & 63, wid = tid >> 6;
  int g = blockIdx.x;
  int rg = g & 7, w = g >> 3;
  int blockB = (rg >> 2) * 16 + (w & 15);
  int blockP = (rg & 3) * 16 + (w >> 4);
  const int lr = lane & 15, lg = lane >> 4;
  const int db = wid >> 1, dp = wid & 1;

  f32x4 acc[4][4];
  #pragma unroll
  for (int m = 0; m < 4; ++m)
    #pragma unroll
    for (int n = 0; n < 4; ++n)
      acc[m][n] = f32x4{0.f, 0.f, 0.f, 0.f};

  const float* Abase = q_emb + (size_t)(blockB * 128) * 768;
  const float* Bbase = p_emb + (size_t)(blockP * 128) * 768;

  for (int kt = 0; kt < 12; ++kt) {
    if (PATH == 1) {
      const unsigned char* qtile = qt + ((size_t)(blockB * 12 + kt)) * 16384;
      const unsigned char* ptile = pt + ((size_t)(blockP * 12 + kt)) * 16384;
      #pragma unroll
      for (int c2 = 0; c2 < 4; ++c2) {
        int chunk = wid * 4 + c2;
        gll16(qtile + chunk * 1024 + lane * 16, (char*)Al + chunk * 1024);
        gll16(ptile + chunk * 1024 + lane * 16, (char*)Bl + chunk * 1024);
      }
    } else {
      const int k0 = kt * 64;
      #pragma unroll
      for (int it = 0; it < 4; ++it) {
        int gg = tid + 256 * it;
        int row = gg >> 3;
        int col = (gg & 7) * 8;
        int off = (row * 128 + col * 2) ^ ((row & 7) << 4);
        const float4* sA = (const float4*)(Abase + (size_t)row * 768 + k0 + col);
        float4 a0 = sA[0], a1 = sA[1];
        uint4 wv;
        wv.x = pack2bf(a0.x, a0.y); wv.y = pack2bf(a0.z, a0.w);
        wv.z = pack2bf(a1.x, a1.y); wv.w = pack2bf(a1.z, a1.w);
        *(uint4*)((char*)Al + off) = wv;
        const float4* sB = (const float4*)(Bbase + (size_t)row * 768 + k0 + col);
        float4 b0 = sB[0], b1 = sB[1];
        wv.x = pack2bf(b0.x, b0.y); wv.y = pack2bf(b0.z, b0.w);
        wv.z = pack2bf(b1.x, b1.y); wv.w = pack2bf(b1.z, b1.w);
        *(uint4*)((char*)Bl + off) = wv;
      }
    }
    __syncthreads();
    #pragma unroll
    for (int ks = 0; ks < 2; ++ks) {
      bf16x8 af[4], bfr[4];
      #pragma unroll
      for (int m = 0; m < 4; ++m) {
        int row = db * 64 + m * 16 + lr;
        int off = (row * 128 + ks * 64 + lg * 16) ^ ((row & 7) << 4);
        af[m] = *(const bf16x8*)((const char*)Al + off);
      }
      #pragma unroll
      for (int n = 0; n < 4; ++n) {
        int row = dp * 64 + n * 16 + lr;
        int off = (row * 128 + ks * 64 + lg * 16) ^ ((row & 7) << 4);
        bfr[n] = *(const bf16x8*)((const char*)Bl + off);
      }
      #pragma unroll
      for (int m = 0; m < 4; ++m)
        #pragma unroll
        for (int n = 0; n < 4; ++n)
          acc[m][n] = __builtin_amdgcn_mfma_f32_16x16x32_bf16(af[m], bfr[n], acc[m][n], 0, 0, 0);
    }
    __syncthreads();
  }

  // epilogue: stage S quadrant in LDS (XOR-swizzled), stream out coalesced NT
  char* Sq = arena + wid * 8192;
  #pragma unroll
  for (int m = 0; m < 4; ++m)
    #pragma unroll
    for (int n = 0; n < 4; ++n) {
      int row = n * 16 + lr;
      int byte = row * 128 + m * 32 + lg * 8;
      int swz = byte ^ ((row & 7) << 4);
      u32x2 wv;
      wv.x = pack2bf(acc[m][n][0], acc[m][n][1]);
      wv.y = pack2bf(acc[m][n][2], acc[m][n][3]);
      *(u32x2*)(Sq + swz) = wv;
    }
  const int pair = (blockB * 2 + db) * 128 + blockP * 2 + dp;
  unsigned short* Sp = Sout + ((size_t)pair << 12);
  #pragma unroll
  for (int i = 0; i < 8; ++i) {
    int base = i * 1024 + lane * 16;
    int swz = base ^ ((lane >> 3) << 4);
    u32x4 v = *(const u32x4*)(Sq + swz);
    __builtin_nontemporal_store(v, (u32x4*)((char*)Sp + base));
  }
}

// ==== kernel 2: linear-bin 2-level count+sum histogram selection ====
#define FOREACH_VALID(BODY)                                   \
  _Pragma("unroll") for (int t = 0; t < 8; ++t) {             \
    if ((pm8 >> t) & 1u) {                                    \
      _Pragma("unroll") for (int jj = 0; jj < 8; ++jj) {      \
        if ((qm8 >> jj) & 1u) {                               \
          unsigned u = vv[t][jj >> 1];                        \
          unsigned bits = (jj & 1) ? (u >> 16) : (u & 0xFFFFu); \
          BODY                                                \
        } } } }

__global__ __launch_bounds__(TB, 6) void dpr_select(
    const unsigned short* __restrict__ S,
    const void* __restrict__ qmr, const void* __restrict__ pmr,
    const float* __restrict__ alpha_raw, const float* __restrict__ beta_raw,
    float* __restrict__ out) {
  __shared__ unsigned l1c[4][256];
  __shared__ float    l1s[4][256];
  __shared__ unsigned l2c[4][512];    // [0:256) top subs, [256:512) bottom subs
  __shared__ float    l2s[4][512];

  const int tid = threadIdx.x, lane = tid & 63, wid = tid >> 6;
  const int pair = blockIdx.x * 4 + wid;
  const int b = pair >> 7, p = pair & 127;

  bool m32 = true;
  {
    const unsigned* qm32 = (const unsigned*)qmr;
    #pragma unroll
    for (int i = 0; i < 8; ++i) m32 = m32 && (qm32[i] <= 1u);
  }
  bool qvb = m32 ? (((const int*)qmr)[b * 64 + lane] != 0)
                 : (((const unsigned char*)qmr)[b * 64 + lane] != 0);
  bool pvb = m32 ? (((const int*)pmr)[p * 64 + lane] != 0)
                 : (((const unsigned char*)pmr)[p * 64 + lane] != 0);
  ull qb = __ballot(qvb);
  ull pb = __ballot(pvb);
  const int n_pair = __popcll(qb) * __popcll(pb);
  if (n_pair == 0) {
    if (lane == 0) out[pair] = -1e9f;
    return;
  }

  int ksel = 4 * n_pair / 10; if (ksel < 1) ksel = 1;
  int lsel = 2 * n_pair / 10; if (lsel < 1) lsel = 1;

  // load this pair's 64 values / lane ONCE into registers
  const unsigned short* Sp = S + ((size_t)pair << 12);
  u32x4 vv[8];
  #pragma unroll
  for (int t = 0; t < 8; ++t)
    vv[t] = __builtin_nontemporal_load((const u32x4*)(Sp + t * 512 + lane * 8));

  const unsigned qm8 = (unsigned)((qb >> ((lane & 7) * 8)) & 0xFFull);
  unsigned pm8 = 0;
  #pragma unroll
  for (int t = 0; t < 8; ++t)
    pm8 |= (unsigned)((pb >> (t * 8 + (lane >> 3))) & 1ull) << t;

  unsigned* c1 = l1c[wid]; float* s1 = l1s[wid];
  unsigned* c2 = l2c[wid]; float* s2 = l2s[wid];

  // T0: masked min / max
  float mn = INFINITY, mx = -INFINITY;
  FOREACH_VALID({
    float x = bf2f(bits);
    mn = fminf(mn, x); mx = fmaxf(mx, x);
  })
  #pragma unroll
  for (int off = 1; off < 64; off <<= 1) {
    mn = fminf(mn, __shfl_xor(mn, off));
    mx = fmaxf(mx, __shfl_xor(mx, off));
  }

  float tsum, topS, botS;
  if (!(mx > mn)) {
    tsum = (float)n_pair * mn;       // all valid values identical
    topS = (float)ksel * mn;
    botS = (float)lsel * mn;
  } else {
    const float sc0 = 256.0f / (mx - mn);

    // zero L1, then T1: linear 256-bin count+sum histogram (low contention)
    ((uint4*)c1)[lane] = uint4{0u, 0u, 0u, 0u};
    ((f32x4*)s1)[lane] = f32x4{0.f, 0.f, 0.f, 0.f};
    FOREACH_VALID({
      float x = bf2f(bits);
      int bn = (int)((x - mn) * sc0);
      bn = bn < 0 ? 0 : (bn > 255 ? 255 : bn);
      atomicAdd(&c1[bn], 1u);
      atomicAdd(&s1[bn], x);
    })

    // L1 scan: lane owns bins [lane*4, lane*4+4)
    uint4 cq = ((const uint4*)c1)[lane];
    f32x4 sq = ((const f32x4*)s1)[lane];
    const unsigned cl0 = cq.x, cl1 = cq.y, cl2 = cq.z, cl3 = cq.w;
    const float sl0 = sq[0], sl1 = sq[1], sl2 = sq[2], sl3 = sq[3];
    const unsigned lc = cl0 + cl1 + cl2 + cl3;
    const float ls = sl0 + sl1 + sl2 + sl3;
    unsigned runC = lc; float runS = ls;
    #pragma unroll
    for (int off = 1; off < 64; off <<= 1) {
      unsigned o = __shfl_down(runC, off);
      float os = __shfl_down(runS, off);
      if (lane + off < 64) { runC += o; runS += os; }
    }
    const unsigned totC = __shfl(runC, 0);
    tsum = __shfl(runS, 0);

    // top locate (suffix: high bins first)
    unsigned aboveC = runC - lc; float aboveS = runS - ls;
    bool fT = ((unsigned)ksel > aboveC) && ((unsigned)ksel <= runC);
    int sbT_ = 0, RT_ = 0; float saT_ = 0.f;
    if (fT) {
      unsigned a = aboveC; float va = aboveS;
      if ((unsigned)ksel <= a + cl3) { sbT_ = 3; RT_ = (int)((unsigned)ksel - a); saT_ = va; }
      else { a += cl3; va += sl3;
      if ((unsigned)ksel <= a + cl2) { sbT_ = 2; RT_ = (int)((unsigned)ksel - a); saT_ = va; }
      else { a += cl2; va += sl2;
      if ((unsigned)ksel <= a + cl1) { sbT_ = 1; RT_ = (int)((unsigned)ksel - a); saT_ = va; }
      else { a += cl1; va += sl1; sbT_ = 0; RT_ = (int)((unsigned)ksel - a); saT_ = va; } } }
      sbT_ += lane * 4;
    }
    ull fmT = __ballot(fT);
    int srcT = fmT ? (int)__builtin_ctzll(fmT) : 0;
    const int sbT = __shfl(sbT_, srcT);
    const int RT = __shfl(RT_, srcT);
    const float saT = __shfl(saT_, srcT);

    // bottom locate (prefix: low bins first)
    unsigned belowC = totC - runC; float belowS = tsum - runS;
    bool fB = ((unsigned)lsel > belowC) && ((unsigned)lsel <= belowC + lc);
    int sbB_ = 0, RB_ = 0; float saB_ = 0.f;
    if (fB) {
      unsigned a = belowC; float vb = belowS;
      if ((unsigned)lsel <= a + cl0) { sbB_ = 0; RB_ = (int)((unsigned)lsel - a); saB_ = vb; }
      else { a += cl0; vb += sl0;
      if ((unsigned)lsel <= a + cl1) { sbB_ = 1; RB_ = (int)((unsigned)lsel - a); saB_ = vb; }
      else { a += cl1; vb += sl1;
      if ((unsigned)lsel <= a + cl2) { sbB_ = 2; RB_ = (int)((unsigned)lsel - a); saB_ = vb; }
      else { a += cl2; vb += sl2; sbB_ = 3; RB_ = (int)((unsigned)lsel - a); saB_ = vb; } } }
      sbB_ += lane * 4;
    }
    ull fmB = __ballot(fB);
    int srcB = fmB ? (int)__builtin_ctzll(fmB) : 0;
    const int sbB = __shfl(sbB_, srcB);
    const int RB = __shfl(RB_, srcB);
    const float saB = __shfl(saB_, srcB);

    // zero L2, then T2: one predicated traversal into both 256-sub-bin hists
    #pragma unroll
    for (int i = 0; i < 2; ++i) {
      ((uint4*)c2)[lane + 64 * i] = uint4{0u, 0u, 0u, 0u};
      ((f32x4*)s2)[lane + 64 * i] = f32x4{0.f, 0.f, 0.f, 0.f};
    }
    const float w0 = (mx - mn) * (1.0f / 256.0f);
    const float loT = mn + w0 * (float)sbT;
    const float loB = mn + w0 * (float)sbB;
    const float sc1 = 65536.0f / (mx - mn);
    FOREACH_VALID({
      float x = bf2f(bits);
      int bn = (int)((x - mn) * sc0);
      bn = bn < 0 ? 0 : (bn > 255 ? 255 : bn);
      if (bn == sbT) {
        int b2 = (int)((x - loT) * sc1);
        b2 = b2 < 0 ? 0 : (b2 > 255 ? 255 : b2);
        atomicAdd(&c2[b2], 1u); atomicAdd(&s2[b2], x);
      }
      if (bn == sbB) {
        int b2 = (int)((x - loB) * sc1);
        b2 = b2 < 0 ? 0 : (b2 > 255 ? 255 : b2);
        atomicAdd(&c2[256 + b2], 1u); atomicAdd(&s2[256 + b2], x);
      }
    })

    // L2 top: suffix scan over 256 sub-bins (4/lane); tail = sub-bin mean * R3
    float inT;
    {
      uint4 c4 = ((const uint4*)c2)[lane];
      f32x4 s4 = ((const f32x4*)s2)[lane];
      const unsigned d0 = c4.x, d1 = c4.y, d2 = c4.z, d3 = c4.w;
      const float e0 = s4[0], e1 = s4[1], e2 = s4[2], e3 = s4[3];
      const unsigned dl = d0 + d1 + d2 + d3;
      const float el = e0 + e1 + e2 + e3;
      unsigned rC = dl; float rS = el;
      #pragma unroll
      for (int off = 1; off < 64; off <<= 1) {
        unsigned o = __shfl_down(rC, off);
        float os = __shfl_down(rS, off);
        if (lane + off < 64) { rC += o; rS += os; }
      }
      unsigned aC = rC - dl; float aS = rS - el;
      bool f = ((unsigned)RT > aC) && ((unsigned)RT <= rC);
      float v = 0.f;
      if (f) {
        unsigned a = aC; float va = aS;
        unsigned cb; float sb2;
        int R3;
        if ((unsigned)RT <= a + d3) { R3 = (int)((unsigned)RT - a); cb = d3; sb2 = e3; }
        else { a += d3; va += e3;
        if ((unsigned)RT <= a + d2) { R3 = (int)((unsigned)RT - a); cb = d2; sb2 = e2; }
        else { a += d2; va += e2;
        if ((unsigned)RT <= a + d1) { R3 = (int)((unsigned)RT - a); cb = d1; sb2 = e1; }
        else { a += d1; va += e1; R3 = (int)((unsigned)RT - a); cb = d0; sb2 = e0; } } }
        v = va + (sb2 / (float)cb) * (float)R3;
      }
      ull fm = __ballot(f);
      int sc = fm ? (int)__builtin_ctzll(fm) : 0;
      inT = __shfl(v, sc);
    }
    // L2 bottom: prefix scan
    float inB;
    {
      uint4 c4 = ((const uint4*)c2)[64 + lane];
      f32x4 s4 = ((const f32x4*)s2)[64 + lane];
      const unsigned d0 = c4.x, d1 = c4.y, d2 = c4.z, d3 = c4.w;
      const float e0 = s4[0], e1 = s4[1], e2 = s4[2], e3 = s4[3];
      const unsigned dl = d0 + d1 + d2 + d3;
      const float el = e0 + e1 + e2 + e3;
      unsigned rC = dl; float rS = el;
      #pragma unroll
      for (int off = 1; off < 64; off <<= 1) {
        unsigned o = __shfl_up(rC, off);
        float os = __shfl_up(rS, off);
        if (lane >= off) { rC += o; rS += os; }
      }
      unsigned bC = rC - dl; float bS = rS - el;
      bool f = ((unsigned)RB > bC) && ((unsigned)RB <= rC);
      float v = 0.f;
      if (f) {
        unsigned a = bC; float vb = bS;
        unsigned cb; float sb2;
        int R3;
        if ((unsigned)RB <= a + d0) { R3 = (int)((unsigned)RB - a); cb = d0; sb2 = e0; }
        else { a += d0; vb += e0;
        if ((unsigned)RB <= a + d1) { R3 = (int)((unsigned)RB - a); cb = d1; sb2 = e1; }
        else { a += d1; vb += e1;
        if ((unsigned)RB <= a + d2) { R3 = (int)((unsigned)RB - a); cb = d2; sb2 = e2; }
        else { a += d2; vb += e2; R3 = (int)((unsigned)RB - a); cb = d3; sb2 = e3; } } }
        v = vb + (sb2 / (float)cb) * (float)R3;
      }
      ull fm = __ballot(f);
      int sc = fm ? (int)__builtin_ctzll(fm) : 0;
      inB = __shfl(v, sc);
    }

    topS = saT + inT;
    botS = saB + inB;
  }

  if (lane == 0) {
    float alpha = log1pf(expf(alpha_raw[0]));
    float beta = log1pf(expf(beta_raw[0]));
    float total_mean = tsum / (float)n_pair;
    float top_mean = topS / (float)ksel;
    float bm = fmaxf(0.0f, -(botS / (float)lsel));
    out[pair] = total_mean + alpha * top_mean - beta * bm;
  }
}
#undef FOREACH_VALID

// ========== last-resort fused fallback (no workspace) ==========
__device__ __forceinline__ void scanTopSum(const unsigned* hC, const float* hS,
                                           int lane, int R, int& selB, int& Rin,
                                           int& cnt, float& sumAbove, float& binSum) {
  uint4 c4 = ((const uint4*)hC)[lane];
  float4 s4 = ((const float4*)hS)[lane];
  unsigned lc = c4.x + c4.y + c4.z + c4.w;
  float ls = s4.x + s4.y + s4.z + s4.w;
  unsigned run = lc; float runv = ls;
  #pragma unroll
  for (int off = 1; off < 64; off <<= 1) {
    unsigned o = __shfl_down(run, off);
    float ov = __shfl_down(runv, off);
    if (lane + off < 64) { run += o; runv += ov; }
  }
  unsigned above = run - lc; float vabove = runv - ls;
  bool found = ((unsigned)R > above) && ((unsigned)R <= run);
  int sb = 0, ri = 0, cc = 0; float sa = 0.f, bs = 0.f;
  if (found) {
    unsigned a = above; float va = vabove;
    if ((unsigned)R <= a + c4.w) { sb = 3; ri = R - (int)a; cc = (int)c4.w; sa = va; bs = s4.w; }
    else { a += c4.w; va += s4.w;
    if ((unsigned)R <= a + c4.z) { sb = 2; ri = R - (int)a; cc = (int)c4.z; sa = va; bs = s4.z; }
    else { a += c4.z; va += s4.z;
    if ((unsigned)R <= a + c4.y) { sb = 1; ri = R - (int)a; cc = (int)c4.y; sa = va; bs = s4.y; }
    else { a += c4.y; va += s4.y; sb = 0; ri = R - (int)a; cc = (int)c4.x; sa = va; bs = s4.x; } } }
    sb += lane * 4;
  }
  ull fm = __ballot(found);
  int src = fm ? (int)__builtin_ctzll(fm) : 0;
  selB = __shfl(sb, src); Rin = __shfl(ri, src);
  cnt = __shfl(cc, src); sumAbove = __shfl(sa, src); binSum = __shfl(bs, src);
}

__device__ __forceinline__ void scanBotSum(const unsigned* hC, const float* hS,
                                           int lane, int R, int& selB, int& Rin,
                                           int& cnt, float& sumBelow, float& binSum) {
  uint4 c4 = ((const uint4*)hC)[lane];
  float4 s4 = ((const float4*)hS)[lane];
  unsigned lc = c4.x + c4.y + c4.z + c4.w;
  float ls = s4.x + s4.y + s4.z + s4.w;
  unsigned run = lc; float runv = ls;
  #pragma unroll
  for (int off = 1; off < 64; off <<= 1) {
    unsigned o = __shfl_up(run, off);
    float ov = __shfl_up(runv, off);
    if (lane >= off) { run += o; runv += ov; }
  }
  unsigned below = run - lc; float vbelow = runv - ls;
  bool found = ((unsigned)R > below) && ((unsigned)R <= run);
  int sb = 0, ri = 0, cc = 0; float sa = 0.f, bs = 0.f;
  if (found) {
    unsigned a = below; float va = vbelow;
    if ((unsigned)R <= a + c4.x) { sb = 0; ri = R - (int)a; cc = (int)c4.x; sa = va; bs = s4.x; }
    else { a += c4.x; va += s4.x;
    if ((unsigned)R <= a + c4.y) { sb = 1; ri = R - (int)a; cc = (int)c4.y; sa = va; bs = s4.y; }
    else { a += c4.y; va += s4.y;
    if ((unsigned)R <= a + c4.z) { sb = 2; ri = R - (int)a; cc = (int)c4.z; sa = va; bs = s4.z; }
    else { a += c4.z; va += s4.z; sb = 3; ri = R - (int)a; cc = (int)c4.w; sa = va; bs = s4.w; } } }
    sb += lane * 4;
  }
  ull fm = __ballot(found);
  int src = fm ? (int)__builtin_ctzll(fm) : 0;
  selB = __shfl(sb, src); Rin = __shfl(ri, src);
  cnt = __shfl(cc, src); sumBelow = __shfl(sa, src); binSum = __shfl(bs, src);
}

__global__ __launch_bounds__(TB, 3) void dpr_fused0(
    const float* __restrict__ q_emb, const float* __restrict__ p_emb,
    const void* __restrict__ qmr, const void* __restrict__ pmr,
    const float* __restrict__ alpha_raw, const float* __restrict__ beta_raw,
    float* __restrict__ out) {
  __shared__ __align__(16) char arena[32768];
  unsigned short* Al = (unsigned short*)arena;
  unsigned short* Bl = (unsigned short*)(arena + 16384);
  const int tid = threadIdx.x, lane = tid & 63, wid = tid >> 6;
  const int bid = blockIdx.x, blockB = bid >> 6, blockP = bid & 63;
  const int lr = lane & 15, lg = lane >> 4;
  const int db = wid >> 1, dp = wid & 1;

  bool m32 = true;
  {
    const unsigned* qm32 = (const unsigned*)qmr;
    #pragma unroll
    for (int i = 0; i < 8; ++i) m32 = m32 && (qm32[i] <= 1u);
  }
  int qrow = (blockB * 2 + db) * 64 + lane;
  int pcolg = (blockP * 2 + dp) * 64 + lane;
  bool qvb = m32 ? (((const int*)qmr)[qrow] != 0) : (((const unsigned char*)qmr)[qrow] != 0);
  bool pvb = m32 ? (((const int*)pmr)[pcolg] != 0) : (((const unsigned char*)pmr)[pcolg] != 0);
  ull qb = __ballot(qvb);
  ull pb = __ballot(pvb);
  const int n_pair = __popcll(qb) * __popcll(pb);

  f32x4 acc[4][4];
  #pragma unroll
  for (int m = 0; m < 4; ++m)
    #pragma unroll
    for (int n = 0; n < 4; ++n)
      acc[m][n] = f32x4{0.f, 0.f, 0.f, 0.f};

  const float* Abase = q_emb + (size_t)(blockB * 128) * 768;
  const float* Bbase = p_emb + (size_t)(blockP * 128) * 768;

  for (int kt = 0; kt < 12; ++kt) {
    const int k0 = kt * 64;
    #pragma unroll
    for (int it = 0; it < 4; ++it) {
      int gg = tid + 256 * it;
      int row = gg >> 3;
      int col = (gg & 7) * 8;
      int off = (row * 128 + col * 2) ^ ((row & 7) << 4);
      const float4* sA = (const float4*)(Abase + (size_t)row * 768 + k0 + col);
      float4 a0 = sA[0], a1 = sA[1];
      uint4 wv;
      wv.x = pack2bf(a0.x, a0.y); wv.y = pack2bf(a0.z, a0.w);
      wv.z = pack2bf(a1.x, a1.y); wv.w = pack2bf(a1.z, a1.w);
      *(uint4*)((char*)Al + off) = wv;
      const float4* sB = (const float4*)(Bbase + (size_t)row * 768 + k0 + col);
      float4 b0 = sB[0], b1 = sB[1];
      wv.x = pack2bf(b0.x, b0.y); wv.y = pack2bf(b0.z, b0.w);
      wv.z = pack2bf(b1.x, b1.y); wv.w = pack2bf(b1.z, b1.w);
      *(uint4*)((char*)Bl + off) = wv;
    }
    __syncthreads();
    #pragma unroll
    for (int ks = 0; ks < 2; ++ks) {
      bf16x8 af[4], bfr[4];
      #pragma unroll
      for (int m = 0; m < 4; ++m) {
        int row = db * 64 + m * 16 + lr;
        int off = (row * 128 + ks * 64 + lg * 16) ^ ((row & 7) << 4);
        af[m] = *(const bf16x8*)((const char*)Al + off);
      }
      #pragma unroll
      for (int n = 0; n < 4; ++n) {
        int row = dp * 64 + n * 16 + lr;
        int off = (row * 128 + ks * 64 + lg * 16) ^ ((row & 7) << 4);
        bfr[n] = *(const bf16x8*)((const char*)Bl + off);
      }
      #pragma unroll
      for (int m = 0; m < 4; ++m)
        #pragma unroll
        for (int n = 0; n < 4; ++n)
          acc[m][n] = __builtin_amdgcn_mfma_f32_16x16x32_bf16(af[m], bfr[n], acc[m][n], 0, 0, 0);
    }
    __syncthreads();
  }

  const int outIdx = (blockB * 2 + db) * 128 + (blockP * 2 + dp);
  if (n_pair == 0) {
    if (lane == 0) out[outIdx] = -1e9f;
    return;
  }

  unsigned vlo = 0, vhi = 0;
  {
    unsigned qn[4], pc[4];
    #pragma unroll
    for (int m = 0; m < 4; ++m) qn[m] = (unsigned)((qb >> (m * 16 + lg * 4)) & 0xFull);
    #pragma unroll
    for (int n = 0; n < 4; ++n) pc[n] = ((pb >> (n * 16 + lr)) & 1ull) ? 0xFu : 0u;
    #pragma unroll
    for (int m = 0; m < 2; ++m)
      #pragma unroll
      for (int n = 0; n < 4; ++n) vlo |= (qn[m] & pc[n]) << ((m * 4 + n) * 4);
    #pragma unroll
    for (int m = 2; m < 4; ++m)
      #pragma unroll
      for (int n = 0; n < 4; ++n) vhi |= (qn[m] & pc[n]) << (((m - 2) * 4 + n) * 4);
  }
  #define VBIT(idx) ((idx) < 32 ? ((vlo >> (idx)) & 1u) : ((vhi >> ((idx) - 32)) & 1u))

  float tsum = 0.f, mn = INFINITY, mx = -INFINITY;
  #pragma unroll
  for (int m = 0; m < 4; ++m)
    #pragma unroll
    for (int n = 0; n < 4; ++n)
      #pragma unroll
      for (int j = 0; j < 4; ++j) {
        const int idx = (m * 4 + n) * 4 + j;
        float x = acc[m][n][j];
        if (VBIT(idx)) { tsum += x; mn = fminf(mn, x); mx = fmaxf(mx, x); }
      }
  #pragma unroll
  for (int off = 1; off < 64; off <<= 1) {
    tsum += __shfl_xor(tsum, off);
    mn = fminf(mn, __shfl_xor(mn, off));
    mx = fmaxf(mx, __shfl_xor(mx, off));
  }

  int ksel = 4 * n_pair / 10; if (ksel < 1) ksel = 1;
  int lsel = 2 * n_pair / 10; if (lsel < 1) lsel = 1;

  unsigned* hC = (unsigned*)(arena + wid * 2048);
  float* hS = (float*)(arena + wid * 2048 + 1024);

  float topS, botS;
  if (!(mx > mn)) {
    topS = (float)ksel * mn;
    botS = (float)lsel * mn;
  } else {
    const float w0 = (mx - mn) * (1.0f / 256.0f);
    const float sc0 = 1.0f / w0;
    ((uint4*)hC)[lane] = uint4{0u, 0u, 0u, 0u};
    ((float4*)hS)[lane] = float4{0.f, 0.f, 0.f, 0.f};
    #pragma unroll
    for (int m = 0; m < 4; ++m)
      #pragma unroll
      for (int n = 0; n < 4; ++n)
        #pragma unroll
        for (int j = 0; j < 4; ++j) {
          const int idx = (m * 4 + n) * 4 + j;
          if (VBIT(idx)) {
            float x = acc[m][n][j];
            int bn = (int)((x - mn) * sc0);
            bn = bn < 0 ? 0 : (bn > 255 ? 255 : bn);
            atomicAdd(&hC[bn], 1u);
            atomicAdd(&hS[bn], x);
          }
        }
    int sbT, RT, cT; float sumA, sBinT;
    int sbB, RB, cB; float sumBlw, sBinB;
    scanTopSum(hC, hS, lane, ksel, sbT, RT, cT, sumA, sBinT);
    scanBotSum(hC, hS, lane, lsel, sbB, RB, cB, sumBlw, sBinB);

    auto refine = [&](bool largest, int sb0, int R0, int c0, float binSum0) -> float {
      if (R0 >= c0) return binSum0;
      float lo1 = mn + w0 * (float)sb0;
      if (!(w0 > 0.f)) return binSum0 * ((float)R0 / (float)c0);
      ((uint4*)hC)[lane] = uint4{0u, 0u, 0u, 0u};
      ((float4*)hS)[lane] = float4{0.f, 0.f, 0.f, 0.f};
      const float sc1 = 256.0f / w0;
      #pragma unroll
      for (int m = 0; m < 4; ++m)
        #pragma unroll
        for (int n = 0; n < 4; ++n)
          #pragma unroll
          for (int j = 0; j < 4; ++j) {
            const int idx = (m * 4 + n) * 4 + j;
            if (VBIT(idx)) {
              float x = acc[m][n][j];
              int b0e = (int)((x - mn) * sc0);
              b0e = b0e < 0 ? 0 : (b0e > 255 ? 255 : b0e);
              if (b0e == sb0) {
                int b1 = (int)((x - lo1) * sc1);
                b1 = b1 < 0 ? 0 : (b1 > 255 ? 255 : b1);
                atomicAdd(&hC[b1], 1u);
                atomicAdd(&hS[b1], x);
              }
            }
          }
      int sb2, R2, c2; float above2, bs2;
      if (largest) scanTopSum(hC, hS, lane, R0, sb2, R2, c2, above2, bs2);
      else         scanBotSum(hC, hS, lane, R0, sb2, R2, c2, above2, bs2);
      if (c2 <= 0) return binSum0 * ((float)R0 / (float)c0);
      return above2 + bs2 * ((float)R2 / (float)c2);
    };

    topS = sumA + refine(true, sbT, RT, cT, sBinT);
    botS = sumBlw + refine(false, sbB, RB, cB, sBinB);
  }
  #undef VBIT

  if (lane == 0) {
    float alpha = log1pf(expf(alpha_raw[0]));
    float beta = log1pf(expf(beta_raw[0]));
    float total_mean = tsum / (float)n_pair;
    float top_mean = topS / (float)ksel;
    float bm = fmaxf(0.0f, -(botS / (float)lsel));
    out[outIdx] = total_mean + alpha * top_mean - beta * bm;
  }
}

extern "C" void kernel_launch(void* const* d_in, const int* in_sizes, int n_in,
                              void* d_out, int out_size, void* d_ws, size_t ws_size,
                              hipStream_t stream) {
  (void)in_sizes; (void)n_in; (void)out_size;
  const float* q_emb = (const float*)d_in[0];
  const float* p_emb = (const float*)d_in[1];
  const void* q_mask = d_in[2];
  const void* p_mask = d_in[3];
  const float* alpha_raw = (const float*)d_in[4];
  const float* beta_raw = (const float*)d_in[5];
  float* out = (float*)d_out;

  if (ws_size >= NEED_T + NEED_S) {
    unsigned char* qt = (unsigned char*)d_ws;
    unsigned char* pt = qt + (size_t)NA_G * 16;
    unsigned short* Sb = (unsigned short*)((unsigned char*)d_ws + NEED_T);
    hipLaunchKernelGGL(convert_pack, dim3((NA_G + NB_G) / 256), dim3(256), 0, stream,
                       q_emb, p_emb, qt, pt);
    hipLaunchKernelGGL((dpr_gemm<1>), dim3(2048), dim3(TB), 0, stream,
                       q_emb, p_emb, qt, pt, Sb);
    hipLaunchKernelGGL(dpr_select, dim3(2048), dim3(TB), 0, stream,
                       Sb, q_mask, p_mask, alpha_raw, beta_raw, out);
  } else if (ws_size >= NEED_S) {
    unsigned short* Sb = (unsigned short*)d_ws;
    hipLaunchKernelGGL((dpr_gemm<0>), dim3(2048), dim3(TB), 0, stream,
                       q_emb, p_emb,
                       (const unsigned char*)nullptr, (const unsigned char*)nullptr, Sb);
    hipLaunchKernelGGL(dpr_select, dim3(2048), dim3(TB), 0, stream,
                       Sb, q_mask, p_mask, alpha_raw, beta_raw, out);
  } else {
    hipLaunchKernelGGL(dpr_fused0, dim3(2048), dim3(TB), 0, stream,
                       q_emb, p_emb, q_mask, p_mask, alpha_raw, beta_raw, out);
  }
}

// Round 12
// 102.954 us; speedup vs baseline: 2.5308x; 2.2966x over previous
//
#include <hip/hip_runtime.h>

#define TB 256
#define NA_G (32 * 12 * 1024)   // 16B-groups in A tiles
#define NB_G (64 * 12 * 1024)   // 16B-groups in B tiles
#define NEED_T ((size_t)(NA_G + NB_G) * 16)          // 18.87 MB bf16 tiles
#define NEED_S ((size_t)8192 * 4096 * 2)             // 67.1 MB bf16 S

typedef __bf16 bf16x8 __attribute__((ext_vector_type(8)));
typedef float f32x4 __attribute__((ext_vector_type(4)));
typedef unsigned u32x4 __attribute__((ext_vector_type(4)));
typedef unsigned u32x2 __attribute__((ext_vector_type(2)));
typedef unsigned long long ull;

__device__ __forceinline__ unsigned pack2bf(float a, float b) {
  unsigned ua = __float_as_uint(a), ub = __float_as_uint(b);
  ua = (ua + 0x7fffu + ((ua >> 16) & 1u)) >> 16;   // RNE f32->bf16
  ub = (ub + 0x7fffu + ((ub >> 16) & 1u)) >> 16;
  return ua | (ub << 16);
}
__device__ __forceinline__ float bf2f(unsigned bits) {
  return __uint_as_float(bits << 16);
}
__device__ __forceinline__ void gll16(const void* g, void* l) {
  __builtin_amdgcn_global_load_lds(
      (const __attribute__((address_space(1))) unsigned*)g,
      (__attribute__((address_space(3))) unsigned*)l, 16, 0, 0);
}

// Pre-convert f32 -> bf16 into XOR-swizzled 128x64 tiles (LDS-image layout)
__global__ __launch_bounds__(256) void convert_pack(
    const float* __restrict__ q, const float* __restrict__ p,
    unsigned char* __restrict__ qt, unsigned char* __restrict__ pt) {
  int g = blockIdx.x * 256 + threadIdx.x;
  const float* src;
  unsigned char* dst;
  if (g < NA_G) { src = q; dst = qt; }
  else { g -= NA_G; src = p; dst = pt; }
  int tile = g >> 10;
  int o = (g & 1023) * 16;
  int row = o >> 7;
  int colb = (o & 127) ^ ((row & 7) << 4);
  int rb = tile / 12, kt = tile - rb * 12;
  const float* s = src + ((size_t)(rb * 128 + row)) * 768 + kt * 64 + (colb >> 1);
  float4 a = ((const float4*)s)[0];
  float4 b = ((const float4*)s)[1];
  uint4 w;
  w.x = pack2bf(a.x, a.y); w.y = pack2bf(a.z, a.w);
  w.z = pack2bf(b.x, b.y); w.w = pack2bf(b.z, b.w);
  *(uint4*)(dst + (size_t)tile * 16384 + o) = w;
}

// ========== kernel 1: LDS-staged GEMM -> S (bf16, coalesced NT stores) ==========
template <int PATH>
__global__ __launch_bounds__(TB, 4) void dpr_gemm(
    const float* __restrict__ q_emb, const float* __restrict__ p_emb,
    const unsigned char* __restrict__ qt, const unsigned char* __restrict__ pt,
    unsigned short* __restrict__ Sout) {
  __shared__ __align__(16) char arena[32768];
  unsigned short* Al = (unsigned short*)arena;
  unsigned short* Bl = (unsigned short*)(arena + 16384);

  const int tid = threadIdx.x, lane = tid & 63, wid = tid >> 6;
  int g = blockIdx.x;
  int rg = g & 7, w = g >> 3;
  int blockB = (rg >> 2) * 16 + (w & 15);
  int blockP = (rg & 3) * 16 + (w >> 4);
  const int lr = lane & 15, lg = lane >> 4;
  const int db = wid >> 1, dp = wid & 1;

  f32x4 acc[4][4];
  #pragma unroll
  for (int m = 0; m < 4; ++m)
    #pragma unroll
    for (int n = 0; n < 4; ++n)
      acc[m][n] = f32x4{0.f, 0.f, 0.f, 0.f};

  const float* Abase = q_emb + (size_t)(blockB * 128) * 768;
  const float* Bbase = p_emb + (size_t)(blockP * 128) * 768;

  for (int kt = 0; kt < 12; ++kt) {
    if (PATH == 1) {
      const unsigned char* qtile = qt + ((size_t)(blockB * 12 + kt)) * 16384;
      const unsigned char* ptile = pt + ((size_t)(blockP * 12 + kt)) * 16384;
      #pragma unroll
      for (int c2 = 0; c2 < 4; ++c2) {
        int chunk = wid * 4 + c2;
        gll16(qtile + chunk * 1024 + lane * 16, (char*)Al + chunk * 1024);
        gll16(ptile + chunk * 1024 + lane * 16, (char*)Bl + chunk * 1024);
      }
    } else {
      const int k0 = kt * 64;
      #pragma unroll
      for (int it = 0; it < 4; ++it) {
        int gg = tid + 256 * it;
        int row = gg >> 3;
        int col = (gg & 7) * 8;
        int off = (row * 128 + col * 2) ^ ((row & 7) << 4);
        const float4* sA = (const float4*)(Abase + (size_t)row * 768 + k0 + col);
        float4 a0 = sA[0], a1 = sA[1];
        uint4 wv;
        wv.x = pack2bf(a0.x, a0.y); wv.y = pack2bf(a0.z, a0.w);
        wv.z = pack2bf(a1.x, a1.y); wv.w = pack2bf(a1.z, a1.w);
        *(uint4*)((char*)Al + off) = wv;
        const float4* sB = (const float4*)(Bbase + (size_t)row * 768 + k0 + col);
        float4 b0 = sB[0], b1 = sB[1];
        wv.x = pack2bf(b0.x, b0.y); wv.y = pack2bf(b0.z, b0.w);
        wv.z = pack2bf(b1.x, b1.y); wv.w = pack2bf(b1.z, b1.w);
        *(uint4*)((char*)Bl + off) = wv;
      }
    }
    __syncthreads();
    #pragma unroll
    for (int ks = 0; ks < 2; ++ks) {
      bf16x8 af[4], bfr[4];
      #pragma unroll
      for (int m = 0; m < 4; ++m) {
        int row = db * 64 + m * 16 + lr;
        int off = (row * 128 + ks * 64 + lg * 16) ^ ((row & 7) << 4);
        af[m] = *(const bf16x8*)((const char*)Al + off);
      }
      #pragma unroll
      for (int n = 0; n < 4; ++n) {
        int row = dp * 64 + n * 16 + lr;
        int off = (row * 128 + ks * 64 + lg * 16) ^ ((row & 7) << 4);
        bfr[n] = *(const bf16x8*)((const char*)Bl + off);
      }
      #pragma unroll
      for (int m = 0; m < 4; ++m)
        #pragma unroll
        for (int n = 0; n < 4; ++n)
          acc[m][n] = __builtin_amdgcn_mfma_f32_16x16x32_bf16(af[m], bfr[n], acc[m][n], 0, 0, 0);
    }
    __syncthreads();
  }

  // epilogue: stage S quadrant in LDS (XOR-swizzled), stream out coalesced NT
  char* Sq = arena + wid * 8192;
  #pragma unroll
  for (int m = 0; m < 4; ++m)
    #pragma unroll
    for (int n = 0; n < 4; ++n) {
      int row = n * 16 + lr;
      int byte = row * 128 + m * 32 + lg * 8;
      int swz = byte ^ ((row & 7) << 4);
      u32x2 wv;
      wv.x = pack2bf(acc[m][n][0], acc[m][n][1]);
      wv.y = pack2bf(acc[m][n][2], acc[m][n][3]);
      *(u32x2*)(Sq + swz) = wv;
    }
  const int pair = (blockB * 2 + db) * 128 + blockP * 2 + dp;
  unsigned short* Sp = Sout + ((size_t)pair << 12);
  #pragma unroll
  for (int i = 0; i < 8; ++i) {
    int base = i * 1024 + lane * 16;
    int swz = base ^ ((lane >> 3) << 4);
    u32x4 v = *(const u32x4*)(Sq + swz);
    __builtin_nontemporal_store(v, (u32x4*)((char*)Sp + base));
  }
}

// ==== kernel 2: linear-bin count-only hist + register-sum selection ====
// NO float LDS atomics (hipcc lowers those to CAS loops — R10/R11 regression).
#define FOREACH_VALID(BODY)                                   \
  _Pragma("unroll") for (int t = 0; t < 8; ++t) {             \
    if ((pm8 >> t) & 1u) {                                    \
      _Pragma("unroll") for (int jj = 0; jj < 8; ++jj) {      \
        if ((qm8 >> jj) & 1u) {                               \
          unsigned u = vv[t][jj >> 1];                        \
          unsigned bits = (jj & 1) ? (u >> 16) : (u & 0xFFFFu); \
          BODY                                                \
        } } } }

__global__ __launch_bounds__(TB, 6) void dpr_select(
    const unsigned short* __restrict__ S,
    const void* __restrict__ qmr, const void* __restrict__ pmr,
    const float* __restrict__ alpha_raw, const float* __restrict__ beta_raw,
    float* __restrict__ out) {
  __shared__ unsigned l1c[4][256];   // per-wave count hist only (4 KB total)

  const int tid = threadIdx.x, lane = tid & 63, wid = tid >> 6;
  const int pair = blockIdx.x * 4 + wid;
  const int b = pair >> 7, p = pair & 127;

  bool m32 = true;
  {
    const unsigned* qm32 = (const unsigned*)qmr;
    #pragma unroll
    for (int i = 0; i < 8; ++i) m32 = m32 && (qm32[i] <= 1u);
  }
  bool qvb = m32 ? (((const int*)qmr)[b * 64 + lane] != 0)
                 : (((const unsigned char*)qmr)[b * 64 + lane] != 0);
  bool pvb = m32 ? (((const int*)pmr)[p * 64 + lane] != 0)
                 : (((const unsigned char*)pmr)[p * 64 + lane] != 0);
  ull qb = __ballot(qvb);
  ull pb = __ballot(pvb);
  const int n_pair = __popcll(qb) * __popcll(pb);
  if (n_pair == 0) {
    if (lane == 0) out[pair] = -1e9f;
    return;
  }

  int ksel = 4 * n_pair / 10; if (ksel < 1) ksel = 1;
  int lsel = 2 * n_pair / 10; if (lsel < 1) lsel = 1;

  // load this pair's 64 values / lane ONCE into registers
  const unsigned short* Sp = S + ((size_t)pair << 12);
  u32x4 vv[8];
  #pragma unroll
  for (int t = 0; t < 8; ++t)
    vv[t] = __builtin_nontemporal_load((const u32x4*)(Sp + t * 512 + lane * 8));

  const unsigned qm8 = (unsigned)((qb >> ((lane & 7) * 8)) & 0xFFull);
  unsigned pm8 = 0;
  #pragma unroll
  for (int t = 0; t < 8; ++t)
    pm8 |= (unsigned)((pb >> (t * 8 + (lane >> 3))) & 1ull) << t;

  unsigned* c1 = l1c[wid];

  // Pass A (masked): min / max / total-sum — registers + shfl only
  float mn = INFINITY, mx = -INFINITY, tsum = 0.f;
  FOREACH_VALID({
    float x = bf2f(bits);
    tsum += x;
    mn = fminf(mn, x); mx = fmaxf(mx, x);
  })
  #pragma unroll
  for (int off = 1; off < 64; off <<= 1) {
    tsum += __shfl_xor(tsum, off);
    mn = fminf(mn, __shfl_xor(mn, off));
    mx = fmaxf(mx, __shfl_xor(mx, off));
  }

  float topS, botS;
  if (!(mx > mn)) {
    topS = (float)ksel * mn;          // all valid values identical
    botS = (float)lsel * mn;
  } else {
    const float sc0 = 256.0f / (mx - mn);

    // Pass B (masked): linear 256-bin COUNT histogram (int atomics only)
    ((uint4*)c1)[lane] = uint4{0u, 0u, 0u, 0u};
    FOREACH_VALID({
      float x = bf2f(bits);
      int bn = (int)((x - mn) * sc0);
      bn = bn < 0 ? 0 : (bn > 255 ? 255 : bn);
      atomicAdd(&c1[bn], 1u);
    })

    // L1 scan: lane owns bins [lane*4, lane*4+4)
    uint4 cq = ((const uint4*)c1)[lane];
    const unsigned cl0 = cq.x, cl1 = cq.y, cl2 = cq.z, cl3 = cq.w;
    const unsigned lc = cl0 + cl1 + cl2 + cl3;
    unsigned runC = lc;
    #pragma unroll
    for (int off = 1; off < 64; off <<= 1) {
      unsigned o = __shfl_down(runC, off);
      if (lane + off < 64) runC += o;
    }
    const unsigned totC = __shfl(runC, 0);

    // top locate (suffix: high bins first)
    unsigned aboveC = runC - lc;
    bool fT = ((unsigned)ksel > aboveC) && ((unsigned)ksel <= runC);
    int sbT_ = 0, RT_ = 0;
    if (fT) {
      unsigned a = aboveC;
      if ((unsigned)ksel <= a + cl3) { sbT_ = 3; RT_ = (int)((unsigned)ksel - a); }
      else { a += cl3;
      if ((unsigned)ksel <= a + cl2) { sbT_ = 2; RT_ = (int)((unsigned)ksel - a); }
      else { a += cl2;
      if ((unsigned)ksel <= a + cl1) { sbT_ = 1; RT_ = (int)((unsigned)ksel - a); }
      else { a += cl1; sbT_ = 0; RT_ = (int)((unsigned)ksel - a); } } }
      sbT_ += lane * 4;
    }
    ull fmT = __ballot(fT);
    int srcT = fmT ? (int)__builtin_ctzll(fmT) : 0;
    const int sbT = __shfl(sbT_, srcT);
    const int RT = __shfl(RT_, srcT);

    // bottom locate (prefix: low bins first)
    unsigned belowC = totC - runC;
    bool fB = ((unsigned)lsel > belowC) && ((unsigned)lsel <= belowC + lc);
    int sbB_ = 0, RB_ = 0;
    if (fB) {
      unsigned a = belowC;
      if ((unsigned)lsel <= a + cl0) { sbB_ = 0; RB_ = (int)((unsigned)lsel - a); }
      else { a += cl0;
      if ((unsigned)lsel <= a + cl1) { sbB_ = 1; RB_ = (int)((unsigned)lsel - a); }
      else { a += cl1;
      if ((unsigned)lsel <= a + cl2) { sbB_ = 2; RB_ = (int)((unsigned)lsel - a); }
      else { a += cl2; sbB_ = 3; RB_ = (int)((unsigned)lsel - a); } } }
      sbB_ += lane * 4;
    }
    ull fmB = __ballot(fB);
    int srcB = fmB ? (int)__builtin_ctzll(fmB) : 0;
    const int sbB = __shfl(sbB_, srcB);
    const int RB = __shfl(RB_, srcB);

    // rank-bin counts (LDS broadcast read, uniform address)
    const unsigned cT = c1[sbT];
    const unsigned cB = c1[sbB];

    // Pass D (masked): predicated register sums, shfl-reduced. No atomics.
    float sT = 0.f, eT = 0.f, sB = 0.f, eB = 0.f;
    FOREACH_VALID({
      float x = bf2f(bits);
      int bn = (int)((x - mn) * sc0);
      bn = bn < 0 ? 0 : (bn > 255 ? 255 : bn);
      sT += (bn > sbT) ? x : 0.f;
      eT += (bn == sbT) ? x : 0.f;
      sB += (bn < sbB) ? x : 0.f;
      eB += (bn == sbB) ? x : 0.f;
    })
    #pragma unroll
    for (int off = 1; off < 64; off <<= 1) {
      sT += __shfl_xor(sT, off);
      eT += __shfl_xor(eT, off);
      sB += __shfl_xor(sB, off);
      eB += __shfl_xor(eB, off);
    }

    // tail = bin-mean * rank-in-bin (error << bf16 GEMM error; see analysis)
    topS = sT + eT * ((float)RT / (float)cT);
    botS = sB + eB * ((float)RB / (float)cB);
  }

  if (lane == 0) {
    float alpha = log1pf(expf(alpha_raw[0]));
    float beta = log1pf(expf(beta_raw[0]));
    float total_mean = tsum / (float)n_pair;
    float top_mean = topS / (float)ksel;
    float bm = fmaxf(0.0f, -(botS / (float)lsel));
    out[pair] = total_mean + alpha * top_mean - beta * bm;
  }
}
#undef FOREACH_VALID

// ========== last-resort fused fallback (no workspace) ==========
__global__ __launch_bounds__(TB, 3) void dpr_fused0(
    const float* __restrict__ q_emb, const float* __restrict__ p_emb,
    const void* __restrict__ qmr, const void* __restrict__ pmr,
    const float* __restrict__ alpha_raw, const float* __restrict__ beta_raw,
    float* __restrict__ out) {
  __shared__ __align__(16) char arena[32768];
  __shared__ unsigned hist4[4][256];
  unsigned short* Al = (unsigned short*)arena;
  unsigned short* Bl = (unsigned short*)(arena + 16384);
  const int tid = threadIdx.x, lane = tid & 63, wid = tid >> 6;
  const int bid = blockIdx.x, blockB = bid >> 6, blockP = bid & 63;
  const int lr = lane & 15, lg = lane >> 4;
  const int db = wid >> 1, dp = wid & 1;

  bool m32 = true;
  {
    const unsigned* qm32 = (const unsigned*)qmr;
    #pragma unroll
    for (int i = 0; i < 8; ++i) m32 = m32 && (qm32[i] <= 1u);
  }
  int qrow = (blockB * 2 + db) * 64 + lane;
  int pcolg = (blockP * 2 + dp) * 64 + lane;
  bool qvb = m32 ? (((const int*)qmr)[qrow] != 0) : (((const unsigned char*)qmr)[qrow] != 0);
  bool pvb = m32 ? (((const int*)pmr)[pcolg] != 0) : (((const unsigned char*)pmr)[pcolg] != 0);
  ull qb = __ballot(qvb);
  ull pb = __ballot(pvb);
  const int n_pair = __popcll(qb) * __popcll(pb);

  f32x4 acc[4][4];
  #pragma unroll
  for (int m = 0; m < 4; ++m)
    #pragma unroll
    for (int n = 0; n < 4; ++n)
      acc[m][n] = f32x4{0.f, 0.f, 0.f, 0.f};

  const float* Abase = q_emb + (size_t)(blockB * 128) * 768;
  const float* Bbase = p_emb + (size_t)(blockP * 128) * 768;

  for (int kt = 0; kt < 12; ++kt) {
    const int k0 = kt * 64;
    #pragma unroll
    for (int it = 0; it < 4; ++it) {
      int gg = tid + 256 * it;
      int row = gg >> 3;
      int col = (gg & 7) * 8;
      int off = (row * 128 + col * 2) ^ ((row & 7) << 4);
      const float4* sA = (const float4*)(Abase + (size_t)row * 768 + k0 + col);
      float4 a0 = sA[0], a1 = sA[1];
      uint4 wv;
      wv.x = pack2bf(a0.x, a0.y); wv.y = pack2bf(a0.z, a0.w);
      wv.z = pack2bf(a1.x, a1.y); wv.w = pack2bf(a1.z, a1.w);
      *(uint4*)((char*)Al + off) = wv;
      const float4* sB = (const float4*)(Bbase + (size_t)row * 768 + k0 + col);
      float4 b0 = sB[0], b1 = sB[1];
      wv.x = pack2bf(b0.x, b0.y); wv.y = pack2bf(b0.z, b0.w);
      wv.z = pack2bf(b1.x, b1.y); wv.w = pack2bf(b1.z, b1.w);
      *(uint4*)((char*)Bl + off) = wv;
    }
    __syncthreads();
    #pragma unroll
    for (int ks = 0; ks < 2; ++ks) {
      bf16x8 af[4], bfr[4];
      #pragma unroll
      for (int m = 0; m < 4; ++m) {
        int row = db * 64 + m * 16 + lr;
        int off = (row * 128 + ks * 64 + lg * 16) ^ ((row & 7) << 4);
        af[m] = *(const bf16x8*)((const char*)Al + off);
      }
      #pragma unroll
      for (int n = 0; n < 4; ++n) {
        int row = dp * 64 + n * 16 + lr;
        int off = (row * 128 + ks * 64 + lg * 16) ^ ((row & 7) << 4);
        bfr[n] = *(const bf16x8*)((const char*)Bl + off);
      }
      #pragma unroll
      for (int m = 0; m < 4; ++m)
        #pragma unroll
        for (int n = 0; n < 4; ++n)
          acc[m][n] = __builtin_amdgcn_mfma_f32_16x16x32_bf16(af[m], bfr[n], acc[m][n], 0, 0, 0);
    }
    __syncthreads();
  }

  const int outIdx = (blockB * 2 + db) * 128 + (blockP * 2 + dp);
  if (n_pair == 0) {
    if (lane == 0) out[outIdx] = -1e9f;
    return;
  }

  unsigned vlo = 0, vhi = 0;
  {
    unsigned qn[4], pc[4];
    #pragma unroll
    for (int m = 0; m < 4; ++m) qn[m] = (unsigned)((qb >> (m * 16 + lg * 4)) & 0xFull);
    #pragma unroll
    for (int n = 0; n < 4; ++n) pc[n] = ((pb >> (n * 16 + lr)) & 1ull) ? 0xFu : 0u;
    #pragma unroll
    for (int m = 0; m < 2; ++m)
      #pragma unroll
      for (int n = 0; n < 4; ++n) vlo |= (qn[m] & pc[n]) << ((m * 4 + n) * 4);
    #pragma unroll
    for (int m = 2; m < 4; ++m)
      #pragma unroll
      for (int n = 0; n < 4; ++n) vhi |= (qn[m] & pc[n]) << (((m - 2) * 4 + n) * 4);
  }
  #define VBIT(idx) ((idx) < 32 ? ((vlo >> (idx)) & 1u) : ((vhi >> ((idx) - 32)) & 1u))

  float tsum = 0.f, mn = INFINITY, mx = -INFINITY;
  #pragma unroll
  for (int m = 0; m < 4; ++m)
    #pragma unroll
    for (int n = 0; n < 4; ++n)
      #pragma unroll
      for (int j = 0; j < 4; ++j) {
        const int idx = (m * 4 + n) * 4 + j;
        float x = acc[m][n][j];
        if (VBIT(idx)) { tsum += x; mn = fminf(mn, x); mx = fmaxf(mx, x); }
      }
  #pragma unroll
  for (int off = 1; off < 64; off <<= 1) {
    tsum += __shfl_xor(tsum, off);
    mn = fminf(mn, __shfl_xor(mn, off));
    mx = fmaxf(mx, __shfl_xor(mx, off));
  }

  int ksel = 4 * n_pair / 10; if (ksel < 1) ksel = 1;
  int lsel = 2 * n_pair / 10; if (lsel < 1) lsel = 1;

  unsigned* c1 = hist4[wid];

  float topS, botS;
  if (!(mx > mn)) {
    topS = (float)ksel * mn;
    botS = (float)lsel * mn;
  } else {
    const float sc0 = 256.0f / (mx - mn);
    ((uint4*)c1)[lane] = uint4{0u, 0u, 0u, 0u};
    #pragma unroll
    for (int m = 0; m < 4; ++m)
      #pragma unroll
      for (int n = 0; n < 4; ++n)
        #pragma unroll
        for (int j = 0; j < 4; ++j) {
          const int idx = (m * 4 + n) * 4 + j;
          if (VBIT(idx)) {
            float x = acc[m][n][j];
            int bn = (int)((x - mn) * sc0);
            bn = bn < 0 ? 0 : (bn > 255 ? 255 : bn);
            atomicAdd(&c1[bn], 1u);
          }
        }

    uint4 cq = ((const uint4*)c1)[lane];
    const unsigned cl0 = cq.x, cl1 = cq.y, cl2 = cq.z, cl3 = cq.w;
    const unsigned lc = cl0 + cl1 + cl2 + cl3;
    unsigned runC = lc;
    #pragma unroll
    for (int off = 1; off < 64; off <<= 1) {
      unsigned o = __shfl_down(runC, off);
      if (lane + off < 64) runC += o;
    }
    const unsigned totC = __shfl(runC, 0);

    unsigned aboveC = runC - lc;
    bool fT = ((unsigned)ksel > aboveC) && ((unsigned)ksel <= runC);
    int sbT_ = 0, RT_ = 0;
    if (fT) {
      unsigned a = aboveC;
      if ((unsigned)ksel <= a + cl3) { sbT_ = 3; RT_ = (int)((unsigned)ksel - a); }
      else { a += cl3;
      if ((unsigned)ksel <= a + cl2) { sbT_ = 2; RT_ = (int)((unsigned)ksel - a); }
      else { a += cl2;
      if ((unsigned)ksel <= a + cl1) { sbT_ = 1; RT_ = (int)((unsigned)ksel - a); }
      else { a += cl1; sbT_ = 0; RT_ = (int)((unsigned)ksel - a); } } }
      sbT_ += lane * 4;
    }
    ull fmT = __ballot(fT);
    int srcT = fmT ? (int)__builtin_ctzll(fmT) : 0;
    const int sbT = __shfl(sbT_, srcT);
    const int RT = __shfl(RT_, srcT);

    unsigned belowC = totC - runC;
    bool fB = ((unsigned)lsel > belowC) && ((unsigned)lsel <= belowC + lc);
    int sbB_ = 0, RB_ = 0;
    if (fB) {
      unsigned a = belowC;
      if ((unsigned)lsel <= a + cl0) { sbB_ = 0; RB_ = (int)((unsigned)lsel - a); }
      else { a += cl0;
      if ((unsigned)lsel <= a + cl1) { sbB_ = 1; RB_ = (int)((unsigned)lsel - a); }
      else { a += cl1;
      if ((unsigned)lsel <= a + cl2) { sbB_ = 2; RB_ = (int)((unsigned)lsel - a); }
      else { a += cl2; sbB_ = 3; RB_ = (int)((unsigned)lsel - a); } } }
      sbB_ += lane * 4;
    }
    ull fmB = __ballot(fB);
    int srcB = fmB ? (int)__builtin_ctzll(fmB) : 0;
    const int sbB = __shfl(sbB_, srcB);
    const int RB = __shfl(RB_, srcB);

    const unsigned cT = c1[sbT];
    const unsigned cB = c1[sbB];

    float sT = 0.f, eT = 0.f, sB = 0.f, eB = 0.f;
    #pragma unroll
    for (int m = 0; m < 4; ++m)
      #pragma unroll
      for (int n = 0; n < 4; ++n)
        #pragma unroll
        for (int j = 0; j < 4; ++j) {
          const int idx = (m * 4 + n) * 4 + j;
          if (VBIT(idx)) {
            float x = acc[m][n][j];
            int bn = (int)((x - mn) * sc0);
            bn = bn < 0 ? 0 : (bn > 255 ? 255 : bn);
            sT += (bn > sbT) ? x : 0.f;
            eT += (bn == sbT) ? x : 0.f;
            sB += (bn < sbB) ? x : 0.f;
            eB += (bn == sbB) ? x : 0.f;
          }
        }
    #pragma unroll
    for (int off = 1; off < 64; off <<= 1) {
      sT += __shfl_xor(sT, off);
      eT += __shfl_xor(eT, off);
      sB += __shfl_xor(sB, off);
      eB += __shfl_xor(eB, off);
    }
    topS = sT + eT * ((float)RT / (float)cT);
    botS = sB + eB * ((float)RB / (float)cB);
  }
  #undef VBIT

  if (lane == 0) {
    float alpha = log1pf(expf(alpha_raw[0]));
    float beta = log1pf(expf(beta_raw[0]));
    float total_mean = tsum / (float)n_pair;
    float top_mean = topS / (float)ksel;
    float bm = fmaxf(0.0f, -(botS / (float)lsel));
    out[outIdx] = total_mean + alpha * top_mean - beta * bm;
  }
}

extern "C" void kernel_launch(void* const* d_in, const int* in_sizes, int n_in,
                              void* d_out, int out_size, void* d_ws, size_t ws_size,
                              hipStream_t stream) {
  (void)in_sizes; (void)n_in; (void)out_size;
  const float* q_emb = (const float*)d_in[0];
  const float* p_emb = (const float*)d_in[1];
  const void* q_mask = d_in[2];
  const void* p_mask = d_in[3];
  const float* alpha_raw = (const float*)d_in[4];
  const float* beta_raw = (const float*)d_in[5];
  float* out = (float*)d_out;

  if (ws_size >= NEED_T + NEED_S) {
    unsigned char* qt = (unsigned char*)d_ws;
    unsigned char* pt = qt + (size_t)NA_G * 16;
    unsigned short* Sb = (unsigned short*)((unsigned char*)d_ws + NEED_T);
    hipLaunchKernelGGL(convert_pack, dim3((NA_G + NB_G) / 256), dim3(256), 0, stream,
                       q_emb, p_emb, qt, pt);
    hipLaunchKernelGGL((dpr_gemm<1>), dim3(2048), dim3(TB), 0, stream,
                       q_emb, p_emb, qt, pt, Sb);
    hipLaunchKernelGGL(dpr_select, dim3(2048), dim3(TB), 0, stream,
                       Sb, q_mask, p_mask, alpha_raw, beta_raw, out);
  } else if (ws_size >= NEED_S) {
    unsigned short* Sb = (unsigned short*)d_ws;
    hipLaunchKernelGGL((dpr_gemm<0>), dim3(2048), dim3(TB), 0, stream,
                       q_emb, p_emb,
                       (const unsigned char*)nullptr, (const unsigned char*)nullptr, Sb);
    hipLaunchKernelGGL(dpr_select, dim3(2048), dim3(TB), 0, stream,
                       Sb, q_mask, p_mask, alpha_raw, beta_raw, out);
  } else {
    hipLaunchKernelGGL(dpr_fused0, dim3(2048), dim3(TB), 0, stream,
                       q_emb, p_emb, q_mask, p_mask, alpha_raw, beta_raw, out);
  }
}